// Round 5
// baseline (2173.795 us; speedup 1.0000x reference)
//
#include <hip/hip_runtime.h>

#define BB 512
#define TT 1024
#define DD 64
#define HH 32
#define CC 4

typedef float f4 __attribute__((ext_vector_type(4)));

__device__ __forceinline__ float rcpf(float x) { return __builtin_amdgcn_rcpf(x); }
__device__ __forceinline__ float sigm(float x) { return rcpf(1.0f + __expf(-x)); }
__device__ __forceinline__ float tanh_f(float x) {
    return 1.0f - 2.0f * rcpf(__expf(2.0f * x) + 1.0f);
}

// ---------------- Kernel 1: zx[b,t,r] = bias0[r] + sum_k x[b,t,k]*w_ih0[r,k] ----------
__global__ void __launch_bounds__(128, 4)
zx_gemm(const float* __restrict__ states,  // [B,T,64]
        const float* __restrict__ w_ih0,   // [128,68]
        const float* __restrict__ b_ih0,
        const float* __restrict__ b_hh0,
        float* __restrict__ zx,            // [B,Tc,128]
        int t0, int tc, int Tc)
{
    const int b = blockIdx.y;
    const int tile = blockIdx.x;
    const int tid = threadIdx.x;
    __shared__ __align__(16) float xs[16][DD];

    const int tbase = t0 + tile * 16;
#pragma unroll
    for (int i = 0; i < 2; ++i) {
        int f = i * 128 + tid;           // float4 id 0..255
        int row = f >> 4, c4 = f & 15;
        int t = tbase + row; if (t > TT - 1) t = TT - 1;
        ((f4*)xs)[f] = *(const f4*)(states + ((size_t)b * TT + t) * DD + c4 * 4);
    }
    __syncthreads();

    const int r = tid;
    const f4* wr = (const f4*)(w_ih0 + (size_t)r * 68);
    f4 w[16];
#pragma unroll
    for (int k = 0; k < 16; ++k) w[k] = wr[k];
    const float bias = b_ih0[r] + b_hh0[r];

    for (int i = 0; i < 16; ++i) {
        int tloc = tile * 16 + i;
        if (tloc >= tc) break;
        const f4* xv = (const f4*)xs[i];
        float a0 = bias, a1 = 0.f, a2 = 0.f, a3 = 0.f;
#pragma unroll
        for (int k = 0; k < 16; ++k) {
            f4 x4 = xv[k];
            a0 = fmaf(w[k].x, x4.x, a0);
            a1 = fmaf(w[k].y, x4.y, a1);
            a2 = fmaf(w[k].z, x4.z, a2);
            a3 = fmaf(w[k].w, x4.w, a3);
        }
        zx[((size_t)b * Tc + tloc) * 128 + r] = (a0 + a1) + (a2 + a3);
    }
}

// ---------------- Kernel 2: single-wave recurrence, zero barriers ----------------
// 64 threads = 1 wave per batch element. Lane l owns gate rows rA=l, rB=l+64.
// half = l>>5: half0 -> (i,g) of unit u=l&31; half1 -> (f,o).
// Gate combine: one shfl_xor(32) pair. h broadcast: LDS write + 8 broadcast
// ds_read_b128 (lockstep wave -> no __syncthreads anywhere).
__global__ void __launch_bounds__(64, 1)
lstm_rec1w(const float* __restrict__ zx,      // [B,Tc,128]
           const float* __restrict__ taup,
           const float* __restrict__ gumbel,  // [T,B,1,C]
           const float* __restrict__ w_ih0,   // [128,68] (ct cols 64..67)
           const float* __restrict__ w_hh0,   // [128,32]
           const float* __restrict__ w_ih1,   // [128,32]
           const float* __restrict__ w_hh1,   // [128,32]
           const float* __restrict__ b_ih1,
           const float* __restrict__ b_hh1,
           const float* __restrict__ w_lin,   // [4,32]
           const float* __restrict__ b_lin,   // [4]
           float* __restrict__ out,           // [B,T,4]
           float* __restrict__ state,         // [B,136]
           int t0, int tc, int Tc, int first)
{
    const int b    = blockIdx.x;
    const int l    = threadIdx.x;     // 0..63
    const int u    = l & 31;
    const int half = l >> 5;
    const int rA   = l;               // rows l and l+64
    const int rB   = l + 64;
    const int c    = l >> 4;          // q channel group

    __shared__ __align__(16) float h1b[HH];
    __shared__ __align__(16) float h2b[HH];

    // ---- per-lane weights -> registers ----
    f4 wctA = *(const f4*)(w_ih0 + (size_t)rA * 68 + 64);
    f4 wctB = *(const f4*)(w_ih0 + (size_t)rB * 68 + 64);
    f4 wh0A[8], wh0B[8], wi1A[8], wi1B[8], wh1A[8], wh1B[8], wlc[8];
#pragma unroll
    for (int k = 0; k < 8; ++k) {
        wh0A[k] = *(const f4*)(w_hh0 + (size_t)rA * HH + 4 * k);
        wh0B[k] = *(const f4*)(w_hh0 + (size_t)rB * HH + 4 * k);
        wi1A[k] = *(const f4*)(w_ih1 + (size_t)rA * HH + 4 * k);
        wi1B[k] = *(const f4*)(w_ih1 + (size_t)rB * HH + 4 * k);
        wh1A[k] = *(const f4*)(w_hh1 + (size_t)rA * HH + 4 * k);
        wh1B[k] = *(const f4*)(w_hh1 + (size_t)rB * HH + 4 * k);
        wlc[k]  = *(const f4*)(w_lin + (size_t)c * HH + 4 * k);
    }
    const float bias1A = b_ih1[rA] + b_hh1[rA];
    const float bias1B = b_ih1[rB] + b_hh1[rB];
    const float inv_tau = rcpf(taup[0]);
    const float blc = b_lin[c];

    // ---- state restore ----
    float* st = state + (size_t)b * 136;
    f4 h1r[8], h2r[8];
    float cst1, cst2, y0, y1, y2, y3;
    if (first) {
#pragma unroll
        for (int k = 0; k < 8; ++k) { h1r[k] = (f4)(0.f); h2r[k] = (f4)(0.f); }
        cst1 = 0.f; cst2 = 0.f; y0 = 1.f; y1 = 0.f; y2 = 0.f; y3 = 0.f;
    } else {
#pragma unroll
        for (int k = 0; k < 8; ++k) {
            h1r[k] = *(const f4*)(st + 4 * k);
            h2r[k] = *(const f4*)(st + 64 + 4 * k);
        }
        cst1 = st[32 + u]; cst2 = st[96 + u];
        y0 = st[128]; y1 = st[129]; y2 = st[130]; y3 = st[131];
    }

    const float* __restrict__ zb = zx + (size_t)b * Tc * 128;
    float* __restrict__ ob = out + (size_t)b * TT * CC;

    float zxA0 = zb[rA], zxB0 = zb[rB];
    float zxA1 = (tc > 1) ? zb[128 + rA] : zxA0;
    float zxB1 = (tc > 1) ? zb[128 + rB] : zxB0;
    float4 gt = *(const float4*)(gumbel + ((size_t)t0 * BB + b) * CC);

    for (int tl = 0; tl < tc; ++tl) {
        // ---- pin weights in VGPRs (asm "redefines" them every iteration,
        // so the allocator cannot rematerialize the global loads) ----
        asm volatile("" : "+v"(wh0A[0]), "+v"(wh0A[1]), "+v"(wh0A[2]), "+v"(wh0A[3]),
                          "+v"(wh0A[4]), "+v"(wh0A[5]), "+v"(wh0A[6]), "+v"(wh0A[7]));
        asm volatile("" : "+v"(wh0B[0]), "+v"(wh0B[1]), "+v"(wh0B[2]), "+v"(wh0B[3]),
                          "+v"(wh0B[4]), "+v"(wh0B[5]), "+v"(wh0B[6]), "+v"(wh0B[7]));
        asm volatile("" : "+v"(wi1A[0]), "+v"(wi1A[1]), "+v"(wi1A[2]), "+v"(wi1A[3]),
                          "+v"(wi1A[4]), "+v"(wi1A[5]), "+v"(wi1A[6]), "+v"(wi1A[7]));
        asm volatile("" : "+v"(wi1B[0]), "+v"(wi1B[1]), "+v"(wi1B[2]), "+v"(wi1B[3]),
                          "+v"(wi1B[4]), "+v"(wi1B[5]), "+v"(wi1B[6]), "+v"(wi1B[7]));
        asm volatile("" : "+v"(wh1A[0]), "+v"(wh1A[1]), "+v"(wh1A[2]), "+v"(wh1A[3]),
                          "+v"(wh1A[4]), "+v"(wh1A[5]), "+v"(wh1A[6]), "+v"(wh1A[7]));
        asm volatile("" : "+v"(wh1B[0]), "+v"(wh1B[1]), "+v"(wh1B[2]), "+v"(wh1B[3]),
                          "+v"(wh1B[4]), "+v"(wh1B[5]), "+v"(wh1B[6]), "+v"(wh1B[7]));
        asm volatile("" : "+v"(wlc[0]), "+v"(wlc[1]), "+v"(wlc[2]), "+v"(wlc[3]),
                          "+v"(wlc[4]), "+v"(wlc[5]), "+v"(wlc[6]), "+v"(wlc[7]));
        asm volatile("" : "+v"(wctA), "+v"(wctB));

        const float zxA = zxA0, zxB = zxB0;
        zxA0 = zxA1; zxB0 = zxB1;
        const int tpf = (tl + 2 < tc) ? tl + 2 : tc - 1;
        zxA1 = zb[(size_t)tpf * 128 + rA];
        zxB1 = zb[(size_t)tpf * 128 + rB];
        const float4 gtc = gt;
        const int tgn = t0 + ((tl + 1 < tc) ? tl + 1 : tc - 1);
        gt = *(const float4*)(gumbel + ((size_t)tgn * BB + b) * CC);

        // ---- layer 0: zA/zB = zx + wct.y + wh0.h1 ----
        float aA0 = zxA, aA1 = 0.f, aA2 = 0.f, aA3 = 0.f;
        float aB0 = zxB, aB1 = 0.f, aB2 = 0.f, aB3 = 0.f;
        aA0 = fmaf(wctA.x, y0, aA0); aA1 = fmaf(wctA.y, y1, aA1);
        aA2 = fmaf(wctA.z, y2, aA2); aA3 = fmaf(wctA.w, y3, aA3);
        aB0 = fmaf(wctB.x, y0, aB0); aB1 = fmaf(wctB.y, y1, aB1);
        aB2 = fmaf(wctB.z, y2, aB2); aB3 = fmaf(wctB.w, y3, aB3);
#pragma unroll
        for (int k = 0; k < 8; ++k) {
            f4 h = h1r[k];
            aA0 = fmaf(wh0A[k].x, h.x, aA0);
            aA1 = fmaf(wh0A[k].y, h.y, aA1);
            aA2 = fmaf(wh0A[k].z, h.z, aA2);
            aA3 = fmaf(wh0A[k].w, h.w, aA3);
            aB0 = fmaf(wh0B[k].x, h.x, aB0);
            aB1 = fmaf(wh0B[k].y, h.y, aB1);
            aB2 = fmaf(wh0B[k].z, h.z, aB2);
            aB3 = fmaf(wh0B[k].w, h.w, aB3);
        }
        float zA = (aA0 + aA1) + (aA2 + aA3);
        float zB = (aB0 + aB1) + (aB2 + aB3);

        // gate combine: half0 has (i,g), half1 has (f,o) of unit u
        float pA = __shfl_xor(zA, 32, 64);
        float pB = __shfl_xor(zB, 32, 64);
        float zi = half ? pA : zA;
        float zf = half ? zA : pA;
        float zg = half ? pB : zB;
        float zo = half ? zB : pB;
        cst1 = sigm(zf) * cst1 + sigm(zi) * tanh_f(zg);
        float h1n = sigm(zo) * tanh_f(cst1);
        if (l < HH) h1b[l] = h1n;
#pragma unroll
        for (int k = 0; k < 8; ++k) h1r[k] = ((const f4*)h1b)[k];  // broadcast allgather

        // ---- layer 1 ----
        aA0 = bias1A; aA1 = 0.f; aA2 = 0.f; aA3 = 0.f;
        aB0 = bias1B; aB1 = 0.f; aB2 = 0.f; aB3 = 0.f;
#pragma unroll
        for (int k = 0; k < 8; ++k) {
            f4 h = h1r[k];
            f4 g2 = h2r[k];
            aA0 = fmaf(wi1A[k].x, h.x, aA0);
            aA1 = fmaf(wi1A[k].y, h.y, aA1);
            aA2 = fmaf(wi1A[k].z, h.z, aA2);
            aA3 = fmaf(wi1A[k].w, h.w, aA3);
            aA0 = fmaf(wh1A[k].x, g2.x, aA0);
            aA1 = fmaf(wh1A[k].y, g2.y, aA1);
            aA2 = fmaf(wh1A[k].z, g2.z, aA2);
            aA3 = fmaf(wh1A[k].w, g2.w, aA3);
            aB0 = fmaf(wi1B[k].x, h.x, aB0);
            aB1 = fmaf(wi1B[k].y, h.y, aB1);
            aB2 = fmaf(wi1B[k].z, h.z, aB2);
            aB3 = fmaf(wi1B[k].w, h.w, aB3);
            aB0 = fmaf(wh1B[k].x, g2.x, aB0);
            aB1 = fmaf(wh1B[k].y, g2.y, aB1);
            aB2 = fmaf(wh1B[k].z, g2.z, aB2);
            aB3 = fmaf(wh1B[k].w, g2.w, aB3);
        }
        zA = (aA0 + aA1) + (aA2 + aA3);
        zB = (aB0 + aB1) + (aB2 + aB3);
        pA = __shfl_xor(zA, 32, 64);
        pB = __shfl_xor(zB, 32, 64);
        zi = half ? pA : zA;
        zf = half ? zA : pA;
        zg = half ? pB : zB;
        zo = half ? zB : pB;
        cst2 = sigm(zf) * cst2 + sigm(zi) * tanh_f(zg);
        float h2n = sigm(zo) * tanh_f(cst2);
        if (l < HH) h2b[l] = h2n;
#pragma unroll
        for (int k = 0; k < 8; ++k) h2r[k] = ((const f4*)h2b)[k];

        // ---- q_c = blc + wlin_c . h2 (redundant per 16-lane group) ----
        float s0 = blc, s1 = 0.f, s2 = 0.f, s3 = 0.f;
#pragma unroll
        for (int k = 0; k < 8; ++k) {
            f4 h = h2r[k];
            s0 = fmaf(wlc[k].x, h.x, s0);
            s1 = fmaf(wlc[k].y, h.y, s1);
            s2 = fmaf(wlc[k].z, h.z, s2);
            s3 = fmaf(wlc[k].w, h.w, s3);
        }
        float qown = (s0 + s1) + (s2 + s3);
        float t1 = __shfl_xor(qown, 16, 64);
        float t2 = __shfl_xor(qown, 32, 64);
        float t3 = __shfl_xor(t1, 32, 64);
        float q0 = (c == 0) ? qown : (c == 1) ? t1 : (c == 2) ? t2 : t3;
        float q1 = (c == 0) ? t1 : (c == 1) ? qown : (c == 2) ? t3 : t2;
        float q2 = (c == 0) ? t2 : (c == 1) ? t3 : (c == 2) ? qown : t1;
        float q3 = (c == 0) ? t3 : (c == 1) ? t2 : (c == 2) ? t1 : qown;
        float l0  = (q0 + gtc.x) * inv_tau;
        float l1_ = (q1 + gtc.y) * inv_tau;
        float l2  = (q2 + gtc.z) * inv_tau;
        float l3  = (q3 + gtc.w) * inv_tau;
        float m = fmaxf(fmaxf(l0, l1_), fmaxf(l2, l3));
        float e0 = __expf(l0 - m), e1 = __expf(l1_ - m);
        float e2 = __expf(l2 - m), e3 = __expf(l3 - m);
        float inv = rcpf((e0 + e1) + (e2 + e3));
        y0 = e0 * inv; y1 = e1 * inv; y2 = e2 * inv; y3 = e3 * inv;

        if (l == 0) *(float4*)(ob + (size_t)(t0 + tl) * CC) = make_float4(y0, y1, y2, y3);
    }

    // ---- state save ----
    if (l < HH) {
        st[l] = h1b[l]; st[64 + l] = h2b[l];
        st[32 + l] = cst1;        // lane l<32 holds c1(u=l)
        st[96 + l] = cst2;
    }
    if (l == 0) { st[128] = y0; st[129] = y1; st[130] = y2; st[131] = y3; }
}

// ---------------- Fallback (verbatim R3 kernel, used only if ws too small) ----------
extern "C" __global__ void __launch_bounds__(128, 2)
lstm_opt_enc(const float* __restrict__ states, const float* __restrict__ taup,
             const float* __restrict__ gumbel, const float* __restrict__ w_ih0,
             const float* __restrict__ w_hh0, const float* __restrict__ b_ih0,
             const float* __restrict__ b_hh0, const float* __restrict__ w_ih1,
             const float* __restrict__ w_hh1, const float* __restrict__ b_ih1,
             const float* __restrict__ b_hh1, const float* __restrict__ w_lin,
             const float* __restrict__ b_lin, float* __restrict__ out)
{
    const int b   = blockIdx.x;
    const int tid = threadIdx.x;
    const int l   = tid & 63;
    const int wv  = tid >> 6;
    const int u0  = l & 15;
    const int g   = l >> 4;
    const int u   = wv * 16 + u0;
    const int r   = g * 32 + u;

    __shared__ __align__(16) float xb[2][DD];
    __shared__ __align__(16) float h1b[2][HH];
    __shared__ __align__(16) float h2b[2][HH];

    float wi0r[68], wh0r[HH], wi1r[HH], wh1r[HH];
#pragma unroll
    for (int k = 0; k < 68; ++k) wi0r[k] = w_ih0[r * 68 + k];
#pragma unroll
    for (int k = 0; k < HH; ++k) wh0r[k] = w_hh0[r * HH + k];
#pragma unroll
    for (int k = 0; k < HH; ++k) wi1r[k] = w_ih1[r * HH + k];
#pragma unroll
    for (int k = 0; k < HH; ++k) wh1r[k] = w_hh1[r * HH + k];
    const float bias0 = b_ih0[r] + b_hh0[r];
    const float bias1 = b_ih1[r] + b_hh1[r];
    const float inv_tau = rcpf(taup[0]);
    const float wl0 = w_lin[g * HH + u0];
    const float wl1 = w_lin[g * HH + u0 + 16];
    const float blc = b_lin[g];

    float cst1 = 0.f, cst2 = 0.f;
    float y0 = 1.f, y1 = 0.f, y2 = 0.f, y3 = 0.f;

    const float* __restrict__ sb = states + (size_t)b * TT * DD;
    float* __restrict__ ob = out + (size_t)b * TT * CC;

    float xr = 0.f;
    if (tid < DD) xr = sb[tid];
    if (tid < HH) { h1b[0][tid] = 0.f; h2b[0][tid] = 0.f; }
    if (tid < DD) { xb[0][tid] = xr; xr = sb[DD + tid]; }
    __syncthreads();

    for (int t = 0; t < TT; ++t) {
        const int p = t & 1, np = p ^ 1;
        if (tid < DD) { xb[np][tid] = xr; }
        const int tn = (t + 2 < TT) ? t + 2 : TT - 1;
        if (tid < DD) { xr = sb[tn * DD + tid]; }
        const float4 gt = *(const float4*)(gumbel + ((size_t)t * BB + b) * CC);

        float a0 = bias0, a1 = 0.f, a2 = 0.f, a3 = 0.f;
        const float4* xv = (const float4*)xb[p];
#pragma unroll
        for (int k = 0; k < 16; ++k) {
            float4 x4 = xv[k];
            a0 = fmaf(wi0r[4 * k + 0], x4.x, a0);
            a1 = fmaf(wi0r[4 * k + 1], x4.y, a1);
            a2 = fmaf(wi0r[4 * k + 2], x4.z, a2);
            a3 = fmaf(wi0r[4 * k + 3], x4.w, a3);
        }
        a0 = fmaf(wi0r[64], y0, a0);
        a1 = fmaf(wi0r[65], y1, a1);
        a2 = fmaf(wi0r[66], y2, a2);
        a3 = fmaf(wi0r[67], y3, a3);
        const float4* h1v = (const float4*)h1b[p];
#pragma unroll
        for (int k = 0; k < 8; ++k) {
            float4 h4 = h1v[k];
            a0 = fmaf(wh0r[4 * k + 0], h4.x, a0);
            a1 = fmaf(wh0r[4 * k + 1], h4.y, a1);
            a2 = fmaf(wh0r[4 * k + 2], h4.z, a2);
            a3 = fmaf(wh0r[4 * k + 3], h4.w, a3);
        }
        float z = (a0 + a1) + (a2 + a3);
        float v1  = __shfl_xor(z, 16, 64);
        float lo  = (g & 1) ? v1 : z;
        float hi  = (g & 1) ? z  : v1;
        float lo2 = __shfl_xor(lo, 32, 64);
        float hi2 = __shfl_xor(hi, 32, 64);
        float zi = (g < 2) ? lo  : lo2;
        float zf = (g < 2) ? hi  : hi2;
        float zg = (g < 2) ? lo2 : lo;
        float zo = (g < 2) ? hi2 : hi;
        cst1 = sigm(zf) * cst1 + sigm(zi) * tanh_f(zg);
        float h1new = sigm(zo) * tanh_f(cst1);
        if (g == 0) h1b[np][u] = h1new;
        __syncthreads();

        a0 = bias1; a1 = 0.f; a2 = 0.f; a3 = 0.f;
        const float4* h1n = (const float4*)h1b[np];
        const float4* h2v = (const float4*)h2b[p];
#pragma unroll
        for (int k = 0; k < 8; ++k) {
            float4 h4 = h1n[k];
            float4 g4 = h2v[k];
            a0 = fmaf(wi1r[4 * k + 0], h4.x, a0);
            a1 = fmaf(wi1r[4 * k + 1], h4.y, a1);
            a2 = fmaf(wi1r[4 * k + 2], h4.z, a2);
            a3 = fmaf(wi1r[4 * k + 3], h4.w, a3);
            a0 = fmaf(wh1r[4 * k + 0], g4.x, a0);
            a1 = fmaf(wh1r[4 * k + 1], g4.y, a1);
            a2 = fmaf(wh1r[4 * k + 2], g4.z, a2);
            a3 = fmaf(wh1r[4 * k + 3], g4.w, a3);
        }
        z = (a0 + a1) + (a2 + a3);
        v1  = __shfl_xor(z, 16, 64);
        lo  = (g & 1) ? v1 : z;
        hi  = (g & 1) ? z  : v1;
        lo2 = __shfl_xor(lo, 32, 64);
        hi2 = __shfl_xor(hi, 32, 64);
        zi = (g < 2) ? lo  : lo2;
        zf = (g < 2) ? hi  : hi2;
        zg = (g < 2) ? lo2 : lo;
        zo = (g < 2) ? hi2 : hi;
        cst2 = sigm(zf) * cst2 + sigm(zi) * tanh_f(zg);
        float h2new = sigm(zo) * tanh_f(cst2);
        if (g == 0) h2b[np][u] = h2new;
        __syncthreads();

        float part = wl0 * h2b[np][u0] + wl1 * h2b[np][u0 + 16];
        part += __shfl_xor(part, 1, 64);
        part += __shfl_xor(part, 2, 64);
        part += __shfl_xor(part, 4, 64);
        part += __shfl_xor(part, 8, 64);
        float qown = part + blc;
        float t1 = __shfl_xor(qown, 16, 64);
        float t2 = __shfl_xor(qown, 32, 64);
        float t3 = __shfl_xor(t1, 32, 64);
        float q0 = (g == 0) ? qown : (g == 1) ? t1 : (g == 2) ? t2 : t3;
        float q1 = (g == 0) ? t1 : (g == 1) ? qown : (g == 2) ? t3 : t2;
        float q2 = (g == 0) ? t2 : (g == 1) ? t3 : (g == 2) ? qown : t1;
        float q3 = (g == 0) ? t3 : (g == 1) ? t2 : (g == 2) ? t1 : qown;
        float l0  = (q0 + gt.x) * inv_tau;
        float l1_ = (q1 + gt.y) * inv_tau;
        float l2  = (q2 + gt.z) * inv_tau;
        float l3  = (q3 + gt.w) * inv_tau;
        float m = fmaxf(fmaxf(l0, l1_), fmaxf(l2, l3));
        float e0 = __expf(l0 - m), e1 = __expf(l1_ - m);
        float e2 = __expf(l2 - m), e3 = __expf(l3 - m);
        float inv = rcpf((e0 + e1) + (e2 + e3));
        y0 = e0 * inv; y1 = e1 * inv; y2 = e2 * inv; y3 = e3 * inv;

        if (tid == 0) *(float4*)(ob + (size_t)t * CC) = make_float4(y0, y1, y2, y3);
    }
}

extern "C" void kernel_launch(void* const* d_in, const int* in_sizes, int n_in,
                              void* d_out, int out_size, void* d_ws, size_t ws_size,
                              hipStream_t stream) {
    const float* states = (const float*)d_in[0];
    const float* tau    = (const float*)d_in[1];
    const float* gumbel = (const float*)d_in[2];
    const float* w_ih0  = (const float*)d_in[3];
    const float* w_hh0  = (const float*)d_in[4];
    const float* b_ih0  = (const float*)d_in[5];
    const float* b_hh0  = (const float*)d_in[6];
    const float* w_ih1  = (const float*)d_in[7];
    const float* w_hh1  = (const float*)d_in[8];
    const float* b_ih1  = (const float*)d_in[9];
    const float* b_hh1  = (const float*)d_in[10];
    const float* w_lin  = (const float*)d_in[11];
    const float* b_lin  = (const float*)d_in[12];
    float* out = (float*)d_out;

    // workspace: zx chunk [B][Tc][128] f32 + carry state [B][136] f32
    const long long state_bytes = (long long)BB * 136 * 4;
    long long avail = (long long)ws_size - state_bytes;
    long long Tcl = avail > 0 ? avail / ((long long)BB * 128 * 4) : 0;
    int Tc = (int)(Tcl > TT ? TT : Tcl);

    if (Tc < 8) {
        hipLaunchKernelGGL(lstm_opt_enc, dim3(BB), dim3(128), 0, stream,
                           states, tau, gumbel, w_ih0, w_hh0, b_ih0, b_hh0,
                           w_ih1, w_hh1, b_ih1, b_hh1, w_lin, b_lin, out);
        return;
    }

    float* zx = (float*)d_ws;
    float* st = (float*)((char*)d_ws + (size_t)BB * Tc * 128 * 4);

    int done = 0, first = 1;
    while (done < TT) {
        int tc = (TT - done < Tc) ? (TT - done) : Tc;
        int tiles = (tc + 15) / 16;
        hipLaunchKernelGGL(zx_gemm, dim3(tiles, BB), dim3(128), 0, stream,
                           states, w_ih0, b_ih0, b_hh0, zx, done, tc, Tc);
        hipLaunchKernelGGL(lstm_rec1w, dim3(BB), dim3(64), 0, stream,
                           zx, tau, gumbel, w_ih0, w_hh0, w_ih1, w_hh1,
                           b_ih1, b_hh1, w_lin, b_lin, out, st, done, tc, Tc, first);
        first = 0;
        done += tc;
    }
}

// Round 6
// 1798.381 us; speedup vs baseline: 1.2088x; 1.2088x over previous
//
#include <hip/hip_runtime.h>

#define BB 512
#define TT 1024
#define DD 64
#define HH 32
#define CC 4

typedef float f4 __attribute__((ext_vector_type(4)));
typedef _Float16 h4 __attribute__((ext_vector_type(4)));

__device__ __forceinline__ float rcpf(float x) { return __builtin_amdgcn_rcpf(x); }
__device__ __forceinline__ float sigm(float x) { return rcpf(1.0f + __expf(-x)); }
__device__ __forceinline__ float tanh_f(float x) {
    return 1.0f - 2.0f * rcpf(__expf(2.0f * x) + 1.0f);
}

__device__ __forceinline__ h4 cvt_h4(f4 a) {
    h4 w;
    w.x = (_Float16)a.x; w.y = (_Float16)a.y;
    w.z = (_Float16)a.z; w.w = (_Float16)a.w;
    return w;
}

// ---------------- Kernel 1: zx[b,t,r] = bias0[r] + sum_k x[b,t,k]*w_ih0[r,k] ----------
__global__ void __launch_bounds__(128, 4)
zx_gemm(const float* __restrict__ states,  // [B,T,64]
        const float* __restrict__ w_ih0,   // [128,68]
        const float* __restrict__ b_ih0,
        const float* __restrict__ b_hh0,
        float* __restrict__ zx,            // [B,Tc,128]
        int t0, int tc, int Tc)
{
    const int b = blockIdx.y;
    const int tile = blockIdx.x;
    const int tid = threadIdx.x;
    __shared__ __align__(16) float xs[16][DD];

    const int tbase = t0 + tile * 16;
#pragma unroll
    for (int i = 0; i < 2; ++i) {
        int f = i * 128 + tid;           // float4 id 0..255
        int row = f >> 4, c4 = f & 15;
        int t = tbase + row; if (t > TT - 1) t = TT - 1;
        ((f4*)xs)[f] = *(const f4*)(states + ((size_t)b * TT + t) * DD + c4 * 4);
    }
    __syncthreads();

    const int r = tid;
    const f4* wr = (const f4*)(w_ih0 + (size_t)r * 68);
    f4 w[16];
#pragma unroll
    for (int k = 0; k < 16; ++k) w[k] = wr[k];
    const float bias = b_ih0[r] + b_hh0[r];

    for (int i = 0; i < 16; ++i) {
        int tloc = tile * 16 + i;
        if (tloc >= tc) break;
        const f4* xv = (const f4*)xs[i];
        float a0 = bias, a1 = 0.f, a2 = 0.f, a3 = 0.f;
#pragma unroll
        for (int k = 0; k < 16; ++k) {
            f4 x4 = xv[k];
            a0 = fmaf(w[k].x, x4.x, a0);
            a1 = fmaf(w[k].y, x4.y, a1);
            a2 = fmaf(w[k].z, x4.z, a2);
            a3 = fmaf(w[k].w, x4.w, a3);
        }
        zx[((size_t)b * Tc + tloc) * 128 + r] = (a0 + a1) + (a2 + a3);
    }
}

// ---------------- Kernel 2: single-wave recurrence, zero barriers, f16 weights -------
// 64 threads = 1 wave per batch element. Lane l owns gate rows rA=l, rB=l+64.
// Recurrent weights packed f16 (v_fma_mix consumes them at f32 FMA rate) so the
// whole working set (~220 VGPR) fits in 256 -> no spill, no in-loop reloads.
// Pins live at loop END: values are "redefined" each iteration (no remat) while
// the body above stays freely schedulable.
__global__ void __launch_bounds__(64, 1)
lstm_rec1w(const float* __restrict__ zx,      // [B,Tc,128]
           const float* __restrict__ taup,
           const float* __restrict__ gumbel,  // [T,B,1,C]
           const float* __restrict__ w_ih0,   // [128,68] (ct cols 64..67)
           const float* __restrict__ w_hh0,   // [128,32]
           const float* __restrict__ w_ih1,   // [128,32]
           const float* __restrict__ w_hh1,   // [128,32]
           const float* __restrict__ b_ih1,
           const float* __restrict__ b_hh1,
           const float* __restrict__ w_lin,   // [4,32]
           const float* __restrict__ b_lin,   // [4]
           float* __restrict__ out,           // [B,T,4]
           float* __restrict__ state,         // [B,136]
           int t0, int tc, int Tc, int first)
{
    const int b    = blockIdx.x;
    const int l    = threadIdx.x;     // 0..63
    const int u    = l & 31;
    const int half = l >> 5;
    const int rA   = l;               // rows l and l+64
    const int rB   = l + 64;
    const int c    = l >> 4;          // q channel group

    __shared__ __align__(16) float h1b[HH];
    __shared__ __align__(16) float h2b[HH];

    // ---- per-lane weights: f32 wct (feedback-critical, tiny), f16 the rest ----
    f4 wctA = *(const f4*)(w_ih0 + (size_t)rA * 68 + 64);
    f4 wctB = *(const f4*)(w_ih0 + (size_t)rB * 68 + 64);
    h4 wh0A[8], wh0B[8], wi1A[8], wi1B[8], wh1A[8], wh1B[8], wlc[8];
#pragma unroll
    for (int k = 0; k < 8; ++k) {
        wh0A[k] = cvt_h4(*(const f4*)(w_hh0 + (size_t)rA * HH + 4 * k));
        wh0B[k] = cvt_h4(*(const f4*)(w_hh0 + (size_t)rB * HH + 4 * k));
        wi1A[k] = cvt_h4(*(const f4*)(w_ih1 + (size_t)rA * HH + 4 * k));
        wi1B[k] = cvt_h4(*(const f4*)(w_ih1 + (size_t)rB * HH + 4 * k));
        wh1A[k] = cvt_h4(*(const f4*)(w_hh1 + (size_t)rA * HH + 4 * k));
        wh1B[k] = cvt_h4(*(const f4*)(w_hh1 + (size_t)rB * HH + 4 * k));
        wlc[k]  = cvt_h4(*(const f4*)(w_lin + (size_t)c * HH + 4 * k));
    }
    const float bias1A = b_ih1[rA] + b_hh1[rA];
    const float bias1B = b_ih1[rB] + b_hh1[rB];
    const float inv_tau = rcpf(taup[0]);
    const float blc = b_lin[c];

    // ---- state restore ----
    float* st = state + (size_t)b * 136;
    f4 h1r[8], h2r[8];
    float cst1, cst2, y0, y1, y2, y3;
    if (first) {
#pragma unroll
        for (int k = 0; k < 8; ++k) { h1r[k] = (f4)(0.f); h2r[k] = (f4)(0.f); }
        cst1 = 0.f; cst2 = 0.f; y0 = 1.f; y1 = 0.f; y2 = 0.f; y3 = 0.f;
    } else {
#pragma unroll
        for (int k = 0; k < 8; ++k) {
            h1r[k] = *(const f4*)(st + 4 * k);
            h2r[k] = *(const f4*)(st + 64 + 4 * k);
        }
        cst1 = st[32 + u]; cst2 = st[96 + u];
        y0 = st[128]; y1 = st[129]; y2 = st[130]; y3 = st[131];
    }

    const float* __restrict__ zb = zx + (size_t)b * Tc * 128;
    float* __restrict__ ob = out + (size_t)b * TT * CC;

    float zxA0 = zb[rA], zxB0 = zb[rB];
    float zxA1 = (tc > 1) ? zb[128 + rA] : zxA0;
    float zxB1 = (tc > 1) ? zb[128 + rB] : zxB0;
    float4 gt = *(const float4*)(gumbel + ((size_t)t0 * BB + b) * CC);

    for (int tl = 0; tl < tc; ++tl) {
        const float zxA = zxA0, zxB = zxB0;
        zxA0 = zxA1; zxB0 = zxB1;
        const int tpf = (tl + 2 < tc) ? tl + 2 : tc - 1;
        zxA1 = zb[(size_t)tpf * 128 + rA];
        zxB1 = zb[(size_t)tpf * 128 + rB];
        const float4 gtc = gt;
        const int tgn = t0 + ((tl + 1 < tc) ? tl + 1 : tc - 1);
        gt = *(const float4*)(gumbel + ((size_t)tgn * BB + b) * CC);

        // ---- layer 0: z = zx + wh0.h1 (+ wct.y last: softmax feedback slack) ----
        float aA0 = zxA, aA1 = 0.f, aA2 = 0.f, aA3 = 0.f;
        float aB0 = zxB, aB1 = 0.f, aB2 = 0.f, aB3 = 0.f;
#pragma unroll
        for (int k = 0; k < 8; ++k) {
            f4 h = h1r[k];
            aA0 = fmaf((float)wh0A[k].x, h.x, aA0);
            aA1 = fmaf((float)wh0A[k].y, h.y, aA1);
            aA2 = fmaf((float)wh0A[k].z, h.z, aA2);
            aA3 = fmaf((float)wh0A[k].w, h.w, aA3);
            aB0 = fmaf((float)wh0B[k].x, h.x, aB0);
            aB1 = fmaf((float)wh0B[k].y, h.y, aB1);
            aB2 = fmaf((float)wh0B[k].z, h.z, aB2);
            aB3 = fmaf((float)wh0B[k].w, h.w, aB3);
        }
        aA0 = fmaf(wctA.x, y0, aA0); aA1 = fmaf(wctA.y, y1, aA1);
        aA2 = fmaf(wctA.z, y2, aA2); aA3 = fmaf(wctA.w, y3, aA3);
        aB0 = fmaf(wctB.x, y0, aB0); aB1 = fmaf(wctB.y, y1, aB1);
        aB2 = fmaf(wctB.z, y2, aB2); aB3 = fmaf(wctB.w, y3, aB3);
        float zA = (aA0 + aA1) + (aA2 + aA3);
        float zB = (aB0 + aB1) + (aB2 + aB3);

        // gate combine: half0 has (i,g), half1 has (f,o) of unit u
        float pA = __shfl_xor(zA, 32, 64);
        float pB = __shfl_xor(zB, 32, 64);
        float zi = half ? pA : zA;
        float zf = half ? zA : pA;
        float zg = half ? pB : zB;
        float zo = half ? zB : pB;
        cst1 = sigm(zf) * cst1 + sigm(zi) * tanh_f(zg);
        float h1n = sigm(zo) * tanh_f(cst1);
        if (l < HH) h1b[l] = h1n;

        // ---- layer 1, part 1: wh1.h2 (independent of h1 allgather -> overlaps it) ----
        float bA0 = bias1A, bA1 = 0.f, bA2 = 0.f, bA3 = 0.f;
        float bB0 = bias1B, bB1 = 0.f, bB2 = 0.f, bB3 = 0.f;
#pragma unroll
        for (int k = 0; k < 8; ++k) {
            f4 g2 = h2r[k];
            bA0 = fmaf((float)wh1A[k].x, g2.x, bA0);
            bA1 = fmaf((float)wh1A[k].y, g2.y, bA1);
            bA2 = fmaf((float)wh1A[k].z, g2.z, bA2);
            bA3 = fmaf((float)wh1A[k].w, g2.w, bA3);
            bB0 = fmaf((float)wh1B[k].x, g2.x, bB0);
            bB1 = fmaf((float)wh1B[k].y, g2.y, bB1);
            bB2 = fmaf((float)wh1B[k].z, g2.z, bB2);
            bB3 = fmaf((float)wh1B[k].w, g2.w, bB3);
        }
        // h1 allgather (broadcast reads, conflict-free)
#pragma unroll
        for (int k = 0; k < 8; ++k) h1r[k] = ((const f4*)h1b)[k];
        // ---- layer 1, part 2: wi1.h1' ----
#pragma unroll
        for (int k = 0; k < 8; ++k) {
            f4 h = h1r[k];
            bA0 = fmaf((float)wi1A[k].x, h.x, bA0);
            bA1 = fmaf((float)wi1A[k].y, h.y, bA1);
            bA2 = fmaf((float)wi1A[k].z, h.z, bA2);
            bA3 = fmaf((float)wi1A[k].w, h.w, bA3);
            bB0 = fmaf((float)wi1B[k].x, h.x, bB0);
            bB1 = fmaf((float)wi1B[k].y, h.y, bB1);
            bB2 = fmaf((float)wi1B[k].z, h.z, bB2);
            bB3 = fmaf((float)wi1B[k].w, h.w, bB3);
        }
        zA = (bA0 + bA1) + (bA2 + bA3);
        zB = (bB0 + bB1) + (bB2 + bB3);
        pA = __shfl_xor(zA, 32, 64);
        pB = __shfl_xor(zB, 32, 64);
        zi = half ? pA : zA;
        zf = half ? zA : pA;
        zg = half ? pB : zB;
        zo = half ? zB : pB;
        cst2 = sigm(zf) * cst2 + sigm(zi) * tanh_f(zg);
        float h2n = sigm(zo) * tanh_f(cst2);
        if (l < HH) h2b[l] = h2n;
#pragma unroll
        for (int k = 0; k < 8; ++k) h2r[k] = ((const f4*)h2b)[k];

        // ---- q_c = blc + wlin_c . h2 (redundant per 16-lane group) ----
        float s0 = blc, s1 = 0.f, s2 = 0.f, s3 = 0.f;
#pragma unroll
        for (int k = 0; k < 8; ++k) {
            f4 h = h2r[k];
            s0 = fmaf((float)wlc[k].x, h.x, s0);
            s1 = fmaf((float)wlc[k].y, h.y, s1);
            s2 = fmaf((float)wlc[k].z, h.z, s2);
            s3 = fmaf((float)wlc[k].w, h.w, s3);
        }
        float qown = (s0 + s1) + (s2 + s3);
        float t1 = __shfl_xor(qown, 16, 64);
        float t2 = __shfl_xor(qown, 32, 64);
        float t3 = __shfl_xor(t1, 32, 64);
        float q0 = (c == 0) ? qown : (c == 1) ? t1 : (c == 2) ? t2 : t3;
        float q1 = (c == 0) ? t1 : (c == 1) ? qown : (c == 2) ? t3 : t2;
        float q2 = (c == 0) ? t2 : (c == 1) ? t3 : (c == 2) ? qown : t1;
        float q3 = (c == 0) ? t3 : (c == 1) ? t2 : (c == 2) ? t1 : qown;
        float l0  = (q0 + gtc.x) * inv_tau;
        float l1_ = (q1 + gtc.y) * inv_tau;
        float l2  = (q2 + gtc.z) * inv_tau;
        float l3  = (q3 + gtc.w) * inv_tau;
        float m = fmaxf(fmaxf(l0, l1_), fmaxf(l2, l3));
        float e0 = __expf(l0 - m), e1 = __expf(l1_ - m);
        float e2 = __expf(l2 - m), e3 = __expf(l3 - m);
        float inv = rcpf((e0 + e1) + (e2 + e3));
        y0 = e0 * inv; y1 = e1 * inv; y2 = e2 * inv; y3 = e3 * inv;

        if (l == 0) *(float4*)(ob + (size_t)(t0 + tl) * CC) = make_float4(y0, y1, y2, y3);

        // ---- weight pins at loop END: redefine per-iteration => no remat/reload,
        // body above schedules freely ----
        asm volatile("" : "+v"(wh0A[0]), "+v"(wh0A[1]), "+v"(wh0A[2]), "+v"(wh0A[3]),
                          "+v"(wh0A[4]), "+v"(wh0A[5]), "+v"(wh0A[6]), "+v"(wh0A[7]),
                          "+v"(wh0B[0]), "+v"(wh0B[1]), "+v"(wh0B[2]), "+v"(wh0B[3]),
                          "+v"(wh0B[4]), "+v"(wh0B[5]), "+v"(wh0B[6]), "+v"(wh0B[7]));
        asm volatile("" : "+v"(wi1A[0]), "+v"(wi1A[1]), "+v"(wi1A[2]), "+v"(wi1A[3]),
                          "+v"(wi1A[4]), "+v"(wi1A[5]), "+v"(wi1A[6]), "+v"(wi1A[7]),
                          "+v"(wi1B[0]), "+v"(wi1B[1]), "+v"(wi1B[2]), "+v"(wi1B[3]),
                          "+v"(wi1B[4]), "+v"(wi1B[5]), "+v"(wi1B[6]), "+v"(wi1B[7]));
        asm volatile("" : "+v"(wh1A[0]), "+v"(wh1A[1]), "+v"(wh1A[2]), "+v"(wh1A[3]),
                          "+v"(wh1A[4]), "+v"(wh1A[5]), "+v"(wh1A[6]), "+v"(wh1A[7]),
                          "+v"(wh1B[0]), "+v"(wh1B[1]), "+v"(wh1B[2]), "+v"(wh1B[3]),
                          "+v"(wh1B[4]), "+v"(wh1B[5]), "+v"(wh1B[6]), "+v"(wh1B[7]));
        asm volatile("" : "+v"(wlc[0]), "+v"(wlc[1]), "+v"(wlc[2]), "+v"(wlc[3]),
                          "+v"(wlc[4]), "+v"(wlc[5]), "+v"(wlc[6]), "+v"(wlc[7]),
                          "+v"(wctA), "+v"(wctB));
    }

    // ---- state save ----
    if (l < HH) {
        st[l] = h1b[l]; st[64 + l] = h2b[l];
        st[32 + l] = cst1;
        st[96 + l] = cst2;
    }
    if (l == 0) { st[128] = y0; st[129] = y1; st[130] = y2; st[131] = y3; }
}

// ---------------- Fallback (verbatim R3 kernel, used only if ws too small) ----------
extern "C" __global__ void __launch_bounds__(128, 2)
lstm_opt_enc(const float* __restrict__ states, const float* __restrict__ taup,
             const float* __restrict__ gumbel, const float* __restrict__ w_ih0,
             const float* __restrict__ w_hh0, const float* __restrict__ b_ih0,
             const float* __restrict__ b_hh0, const float* __restrict__ w_ih1,
             const float* __restrict__ w_hh1, const float* __restrict__ b_ih1,
             const float* __restrict__ b_hh1, const float* __restrict__ w_lin,
             const float* __restrict__ b_lin, float* __restrict__ out)
{
    const int b   = blockIdx.x;
    const int tid = threadIdx.x;
    const int l   = tid & 63;
    const int wv  = tid >> 6;
    const int u0  = l & 15;
    const int g   = l >> 4;
    const int u   = wv * 16 + u0;
    const int r   = g * 32 + u;

    __shared__ __align__(16) float xb[2][DD];
    __shared__ __align__(16) float h1b[2][HH];
    __shared__ __align__(16) float h2b[2][HH];

    float wi0r[68], wh0r[HH], wi1r[HH], wh1r[HH];
#pragma unroll
    for (int k = 0; k < 68; ++k) wi0r[k] = w_ih0[r * 68 + k];
#pragma unroll
    for (int k = 0; k < HH; ++k) wh0r[k] = w_hh0[r * HH + k];
#pragma unroll
    for (int k = 0; k < HH; ++k) wi1r[k] = w_ih1[r * HH + k];
#pragma unroll
    for (int k = 0; k < HH; ++k) wh1r[k] = w_hh1[r * HH + k];
    const float bias0 = b_ih0[r] + b_hh0[r];
    const float bias1 = b_ih1[r] + b_hh1[r];
    const float inv_tau = rcpf(taup[0]);
    const float wl0 = w_lin[g * HH + u0];
    const float wl1 = w_lin[g * HH + u0 + 16];
    const float blc = b_lin[g];

    float cst1 = 0.f, cst2 = 0.f;
    float y0 = 1.f, y1 = 0.f, y2 = 0.f, y3 = 0.f;

    const float* __restrict__ sb = states + (size_t)b * TT * DD;
    float* __restrict__ ob = out + (size_t)b * TT * CC;

    float xr = 0.f;
    if (tid < DD) xr = sb[tid];
    if (tid < HH) { h1b[0][tid] = 0.f; h2b[0][tid] = 0.f; }
    if (tid < DD) { xb[0][tid] = xr; xr = sb[DD + tid]; }
    __syncthreads();

    for (int t = 0; t < TT; ++t) {
        const int p = t & 1, np = p ^ 1;
        if (tid < DD) { xb[np][tid] = xr; }
        const int tn = (t + 2 < TT) ? t + 2 : TT - 1;
        if (tid < DD) { xr = sb[tn * DD + tid]; }
        const float4 gt = *(const float4*)(gumbel + ((size_t)t * BB + b) * CC);

        float a0 = bias0, a1 = 0.f, a2 = 0.f, a3 = 0.f;
        const float4* xv = (const float4*)xb[p];
#pragma unroll
        for (int k = 0; k < 16; ++k) {
            float4 x4 = xv[k];
            a0 = fmaf(wi0r[4 * k + 0], x4.x, a0);
            a1 = fmaf(wi0r[4 * k + 1], x4.y, a1);
            a2 = fmaf(wi0r[4 * k + 2], x4.z, a2);
            a3 = fmaf(wi0r[4 * k + 3], x4.w, a3);
        }
        a0 = fmaf(wi0r[64], y0, a0);
        a1 = fmaf(wi0r[65], y1, a1);
        a2 = fmaf(wi0r[66], y2, a2);
        a3 = fmaf(wi0r[67], y3, a3);
        const float4* h1v = (const float4*)h1b[p];
#pragma unroll
        for (int k = 0; k < 8; ++k) {
            float4 h4 = h1v[k];
            a0 = fmaf(wh0r[4 * k + 0], h4.x, a0);
            a1 = fmaf(wh0r[4 * k + 1], h4.y, a1);
            a2 = fmaf(wh0r[4 * k + 2], h4.z, a2);
            a3 = fmaf(wh0r[4 * k + 3], h4.w, a3);
        }
        float z = (a0 + a1) + (a2 + a3);
        float v1  = __shfl_xor(z, 16, 64);
        float lo  = (g & 1) ? v1 : z;
        float hi  = (g & 1) ? z  : v1;
        float lo2 = __shfl_xor(lo, 32, 64);
        float hi2 = __shfl_xor(hi, 32, 64);
        float zi = (g < 2) ? lo  : lo2;
        float zf = (g < 2) ? hi  : hi2;
        float zg = (g < 2) ? lo2 : lo;
        float zo = (g < 2) ? hi2 : hi;
        cst1 = sigm(zf) * cst1 + sigm(zi) * tanh_f(zg);
        float h1new = sigm(zo) * tanh_f(cst1);
        if (g == 0) h1b[np][u] = h1new;
        __syncthreads();

        a0 = bias1; a1 = 0.f; a2 = 0.f; a3 = 0.f;
        const float4* h1n = (const float4*)h1b[np];
        const float4* h2v = (const float4*)h2b[p];
#pragma unroll
        for (int k = 0; k < 8; ++k) {
            float4 h4 = h1n[k];
            float4 g4 = h2v[k];
            a0 = fmaf(wi1r[4 * k + 0], h4.x, a0);
            a1 = fmaf(wi1r[4 * k + 1], h4.y, a1);
            a2 = fmaf(wi1r[4 * k + 2], h4.z, a2);
            a3 = fmaf(wi1r[4 * k + 3], h4.w, a3);
            a0 = fmaf(wh1r[4 * k + 0], g4.x, a0);
            a1 = fmaf(wh1r[4 * k + 1], g4.y, a1);
            a2 = fmaf(wh1r[4 * k + 2], g4.z, a2);
            a3 = fmaf(wh1r[4 * k + 3], g4.w, a3);
        }
        z = (a0 + a1) + (a2 + a3);
        v1  = __shfl_xor(z, 16, 64);
        lo  = (g & 1) ? v1 : z;
        hi  = (g & 1) ? z  : v1;
        lo2 = __shfl_xor(lo, 32, 64);
        hi2 = __shfl_xor(hi, 32, 64);
        zi = (g < 2) ? lo  : lo2;
        zf = (g < 2) ? hi  : hi2;
        zg = (g < 2) ? lo2 : lo;
        zo = (g < 2) ? hi2 : hi;
        cst2 = sigm(zf) * cst2 + sigm(zi) * tanh_f(zg);
        float h2new = sigm(zo) * tanh_f(cst2);
        if (g == 0) h2b[np][u] = h2new;
        __syncthreads();

        float part = wl0 * h2b[np][u0] + wl1 * h2b[np][u0 + 16];
        part += __shfl_xor(part, 1, 64);
        part += __shfl_xor(part, 2, 64);
        part += __shfl_xor(part, 4, 64);
        part += __shfl_xor(part, 8, 64);
        float qown = part + blc;
        float t1 = __shfl_xor(qown, 16, 64);
        float t2 = __shfl_xor(qown, 32, 64);
        float t3 = __shfl_xor(t1, 32, 64);
        float q0 = (g == 0) ? qown : (g == 1) ? t1 : (g == 2) ? t2 : t3;
        float q1 = (g == 0) ? t1 : (g == 1) ? qown : (g == 2) ? t3 : t2;
        float q2 = (g == 0) ? t2 : (g == 1) ? t3 : (g == 2) ? qown : t1;
        float q3 = (g == 0) ? t3 : (g == 1) ? t2 : (g == 2) ? t1 : qown;
        float l0  = (q0 + gt.x) * inv_tau;
        float l1_ = (q1 + gt.y) * inv_tau;
        float l2  = (q2 + gt.z) * inv_tau;
        float l3  = (q3 + gt.w) * inv_tau;
        float m = fmaxf(fmaxf(l0, l1_), fmaxf(l2, l3));
        float e0 = __expf(l0 - m), e1 = __expf(l1_ - m);
        float e2 = __expf(l2 - m), e3 = __expf(l3 - m);
        float inv = rcpf((e0 + e1) + (e2 + e3));
        y0 = e0 * inv; y1 = e1 * inv; y2 = e2 * inv; y3 = e3 * inv;

        if (tid == 0) *(float4*)(ob + (size_t)t * CC) = make_float4(y0, y1, y2, y3);
    }
}

extern "C" void kernel_launch(void* const* d_in, const int* in_sizes, int n_in,
                              void* d_out, int out_size, void* d_ws, size_t ws_size,
                              hipStream_t stream) {
    const float* states = (const float*)d_in[0];
    const float* tau    = (const float*)d_in[1];
    const float* gumbel = (const float*)d_in[2];
    const float* w_ih0  = (const float*)d_in[3];
    const float* w_hh0  = (const float*)d_in[4];
    const float* b_ih0  = (const float*)d_in[5];
    const float* b_hh0  = (const float*)d_in[6];
    const float* w_ih1  = (const float*)d_in[7];
    const float* w_hh1  = (const float*)d_in[8];
    const float* b_ih1  = (const float*)d_in[9];
    const float* b_hh1  = (const float*)d_in[10];
    const float* w_lin  = (const float*)d_in[11];
    const float* b_lin  = (const float*)d_in[12];
    float* out = (float*)d_out;

    // workspace: zx chunk [B][Tc][128] f32 + carry state [B][136] f32
    const long long state_bytes = (long long)BB * 136 * 4;
    long long avail = (long long)ws_size - state_bytes;
    long long Tcl = avail > 0 ? avail / ((long long)BB * 128 * 4) : 0;
    int Tc = (int)(Tcl > TT ? TT : Tcl);

    if (Tc < 8) {
        hipLaunchKernelGGL(lstm_opt_enc, dim3(BB), dim3(128), 0, stream,
                           states, tau, gumbel, w_ih0, w_hh0, b_ih0, b_hh0,
                           w_ih1, w_hh1, b_ih1, b_hh1, w_lin, b_lin, out);
        return;
    }

    float* zx = (float*)d_ws;
    float* st = (float*)((char*)d_ws + (size_t)BB * Tc * 128 * 4);

    int done = 0, first = 1;
    while (done < TT) {
        int tc = (TT - done < Tc) ? (TT - done) : Tc;
        int tiles = (tc + 15) / 16;
        hipLaunchKernelGGL(zx_gemm, dim3(tiles, BB), dim3(128), 0, stream,
                           states, w_ih0, b_ih0, b_hh0, zx, done, tc, Tc);
        hipLaunchKernelGGL(lstm_rec1w, dim3(BB), dim3(64), 0, stream,
                           zx, tau, gumbel, w_ih0, w_hh0, w_ih1, w_hh1,
                           b_ih1, b_hh1, w_lin, b_lin, out, st, done, tc, Tc, first);
        first = 0;
        done += tc;
    }
}

// Round 7
// 1388.381 us; speedup vs baseline: 1.5657x; 1.2953x over previous
//
#include <hip/hip_runtime.h>

#define BB 512
#define TT 1024
#define DD 64
#define HH 32
#define CC 4
#define TILE 16

typedef float f4 __attribute__((ext_vector_type(4)));
typedef _Float16 h4 __attribute__((ext_vector_type(4)));

__device__ __forceinline__ float rcpf(float x) { return __builtin_amdgcn_rcpf(x); }
__device__ __forceinline__ float sigm(float x) { return rcpf(1.0f + __expf(-x)); }
__device__ __forceinline__ float tanh_f(float x) {
    return 1.0f - 2.0f * rcpf(__expf(2.0f * x) + 1.0f);
}

__device__ __forceinline__ h4 cvt_h4(f4 a) {
    h4 w;
    w.x = (_Float16)a.x; w.y = (_Float16)a.y;
    w.z = (_Float16)a.z; w.w = (_Float16)a.w;
    return w;
}

// ---------------- Kernel 1: zx[b,t,r] = bias0[r] + sum_k x[b,t,k]*w_ih0[r,k] ----------
__global__ void __launch_bounds__(128, 4)
zx_gemm(const float* __restrict__ states,  // [B,T,64]
        const float* __restrict__ w_ih0,   // [128,68]
        const float* __restrict__ b_ih0,
        const float* __restrict__ b_hh0,
        float* __restrict__ zx,            // [B,Tc,128]
        int t0, int tc, int Tc)
{
    const int b = blockIdx.y;
    const int tile = blockIdx.x;
    const int tid = threadIdx.x;
    __shared__ __align__(16) float xs[16][DD];

    const int tbase = t0 + tile * 16;
#pragma unroll
    for (int i = 0; i < 2; ++i) {
        int f = i * 128 + tid;           // float4 id 0..255
        int row = f >> 4, c4 = f & 15;
        int t = tbase + row; if (t > TT - 1) t = TT - 1;
        ((f4*)xs)[f] = *(const f4*)(states + ((size_t)b * TT + t) * DD + c4 * 4);
    }
    __syncthreads();

    const int r = tid;
    const f4* wr = (const f4*)(w_ih0 + (size_t)r * 68);
    f4 w[16];
#pragma unroll
    for (int k = 0; k < 16; ++k) w[k] = wr[k];
    const float bias = b_ih0[r] + b_hh0[r];

    for (int i = 0; i < 16; ++i) {
        int tloc = tile * 16 + i;
        if (tloc >= tc) break;
        const f4* xv = (const f4*)xs[i];
        float a0 = bias, a1 = 0.f, a2 = 0.f, a3 = 0.f;
#pragma unroll
        for (int k = 0; k < 16; ++k) {
            f4 x4 = xv[k];
            a0 = fmaf(w[k].x, x4.x, a0);
            a1 = fmaf(w[k].y, x4.y, a1);
            a2 = fmaf(w[k].z, x4.z, a2);
            a3 = fmaf(w[k].w, x4.w, a3);
        }
        zx[((size_t)b * Tc + tloc) * 128 + r] = (a0 + a1) + (a2 + a3);
    }
}

// ---------------- Kernel 2: single-wave recurrence, tile-staged LDS inputs ----------
// 64 threads = 1 wave per batch element; zero barriers. Per 16-step tile:
// burst-load the 16x128 zx tile (8 coalesced float4/lane) + gumbel (1 float4/lane)
// into registers at tile start, consume the PREVIOUS tile from LDS, then one
// vmcnt wait (16 steps of slack) + ds_write into the other LDS buffer.
// Per-step path touches only LDS + registers.
__global__ void __launch_bounds__(64, 1)
lstm_rec1w(const float* __restrict__ zx,      // [B,Tc,128]
           const float* __restrict__ taup,
           const float* __restrict__ gumbel,  // [T,B,1,C]
           const float* __restrict__ w_ih0,   // [128,68] (ct cols 64..67)
           const float* __restrict__ w_hh0,   // [128,32]
           const float* __restrict__ w_ih1,   // [128,32]
           const float* __restrict__ w_hh1,   // [128,32]
           const float* __restrict__ b_ih1,
           const float* __restrict__ b_hh1,
           const float* __restrict__ w_lin,   // [4,32]
           const float* __restrict__ b_lin,   // [4]
           float* __restrict__ out,           // [B,T,4]
           float* __restrict__ state,         // [B,136]
           int t0, int tc, int Tc, int first)
{
    const int b    = blockIdx.x;
    const int l    = threadIdx.x;     // 0..63
    const int u    = l & 31;
    const int half = l >> 5;
    const int rA   = l;               // rows l and l+64
    const int rB   = l + 64;
    const int c    = l >> 4;          // q channel group

    __shared__ __align__(16) float zbuf[2][TILE][128];   // 16 KB
    __shared__ __align__(16) float4 gbuf[2][TILE];
    __shared__ __align__(16) float h1b[HH];
    __shared__ __align__(16) float h2b[HH];

    // ---- per-lane weights: f32 wct (feedback-critical, tiny), f16 the rest ----
    f4 wctA = *(const f4*)(w_ih0 + (size_t)rA * 68 + 64);
    f4 wctB = *(const f4*)(w_ih0 + (size_t)rB * 68 + 64);
    h4 wh0A[8], wh0B[8], wi1A[8], wi1B[8], wh1A[8], wh1B[8], wlc[8];
#pragma unroll
    for (int k = 0; k < 8; ++k) {
        wh0A[k] = cvt_h4(*(const f4*)(w_hh0 + (size_t)rA * HH + 4 * k));
        wh0B[k] = cvt_h4(*(const f4*)(w_hh0 + (size_t)rB * HH + 4 * k));
        wi1A[k] = cvt_h4(*(const f4*)(w_ih1 + (size_t)rA * HH + 4 * k));
        wi1B[k] = cvt_h4(*(const f4*)(w_ih1 + (size_t)rB * HH + 4 * k));
        wh1A[k] = cvt_h4(*(const f4*)(w_hh1 + (size_t)rA * HH + 4 * k));
        wh1B[k] = cvt_h4(*(const f4*)(w_hh1 + (size_t)rB * HH + 4 * k));
        wlc[k]  = cvt_h4(*(const f4*)(w_lin + (size_t)c * HH + 4 * k));
    }
    const float bias1A = b_ih1[rA] + b_hh1[rA];
    const float bias1B = b_ih1[rB] + b_hh1[rB];
    const float inv_tau = rcpf(taup[0]);
    const float blc = b_lin[c];

    // ---- state restore ----
    float* st = state + (size_t)b * 136;
    f4 h1r[8], h2r[8];
    float cst1, cst2, y0, y1, y2, y3;
    if (first) {
#pragma unroll
        for (int k = 0; k < 8; ++k) { h1r[k] = (f4)(0.f); h2r[k] = (f4)(0.f); }
        cst1 = 0.f; cst2 = 0.f; y0 = 1.f; y1 = 0.f; y2 = 0.f; y3 = 0.f;
    } else {
#pragma unroll
        for (int k = 0; k < 8; ++k) {
            h1r[k] = *(const f4*)(st + 4 * k);
            h2r[k] = *(const f4*)(st + 64 + 4 * k);
        }
        cst1 = st[32 + u]; cst2 = st[96 + u];
        y0 = st[128]; y1 = st[129]; y2 = st[130]; y3 = st[131];
    }

    const float* __restrict__ zb = zx + (size_t)b * Tc * 128;
    float* __restrict__ ob = out + (size_t)b * TT * CC;
    const int NT = tc / TILE;

    // staging address decomposition: float4 id f = i*64 + l -> row = i*2 + (l>>5), col4 = l&31
    const int srow = l >> 5;
    const int scol = l & 31;

    // ---- prologue: stage tile 0 into buffer 0 ----
    {
        f4 sz[8];
#pragma unroll
        for (int i = 0; i < 8; ++i)
            sz[i] = *(const f4*)(zb + (size_t)(i * 2 + srow) * 128 + scol * 4);
        float4 gv = *(const float4*)(gumbel + ((size_t)(t0 + (l & 15)) * BB + b) * CC);
#pragma unroll
        for (int i = 0; i < 8; ++i)
            ((f4*)&zbuf[0][0][0])[i * 64 + l] = sz[i];
        if (l < 16) gbuf[0][l] = gv;
    }

    for (int k = 0; k < NT; ++k) {
        const int cb = k & 1, nb = cb ^ 1;
        const int kn = (k + 1 < NT) ? k + 1 : 0;   // clamped prefetch tile

        // ---- issue next-tile burst loads (consumed after the 16 steps) ----
        f4 sz[8];
        const float* tb = zb + (size_t)kn * TILE * 128;
#pragma unroll
        for (int i = 0; i < 8; ++i)
            sz[i] = *(const f4*)(tb + (size_t)(i * 2 + srow) * 128 + scol * 4);
        float4 gv = *(const float4*)(gumbel +
                        ((size_t)(t0 + kn * TILE + (l & 15)) * BB + b) * CC);

#pragma unroll 1
        for (int s = 0; s < TILE; ++s) {
            const float zxA = zbuf[cb][s][rA];
            const float zxB = zbuf[cb][s][rB];
            const float4 gtc = gbuf[cb][s];

            // ---- layer 0: z = zx + wh0.h1 (+ wct.y last: softmax feedback slack) ----
            float aA0 = zxA, aA1 = 0.f, aA2 = 0.f, aA3 = 0.f;
            float aB0 = zxB, aB1 = 0.f, aB2 = 0.f, aB3 = 0.f;
#pragma unroll
            for (int k2 = 0; k2 < 8; ++k2) {
                f4 h = h1r[k2];
                aA0 = fmaf((float)wh0A[k2].x, h.x, aA0);
                aA1 = fmaf((float)wh0A[k2].y, h.y, aA1);
                aA2 = fmaf((float)wh0A[k2].z, h.z, aA2);
                aA3 = fmaf((float)wh0A[k2].w, h.w, aA3);
                aB0 = fmaf((float)wh0B[k2].x, h.x, aB0);
                aB1 = fmaf((float)wh0B[k2].y, h.y, aB1);
                aB2 = fmaf((float)wh0B[k2].z, h.z, aB2);
                aB3 = fmaf((float)wh0B[k2].w, h.w, aB3);
            }
            aA0 = fmaf(wctA.x, y0, aA0); aA1 = fmaf(wctA.y, y1, aA1);
            aA2 = fmaf(wctA.z, y2, aA2); aA3 = fmaf(wctA.w, y3, aA3);
            aB0 = fmaf(wctB.x, y0, aB0); aB1 = fmaf(wctB.y, y1, aB1);
            aB2 = fmaf(wctB.z, y2, aB2); aB3 = fmaf(wctB.w, y3, aB3);
            float zA = (aA0 + aA1) + (aA2 + aA3);
            float zB = (aB0 + aB1) + (aB2 + aB3);

            // gate combine: half0 has (i,g), half1 has (f,o) of unit u
            float pA = __shfl_xor(zA, 32, 64);
            float pB = __shfl_xor(zB, 32, 64);
            float zi = half ? pA : zA;
            float zf = half ? zA : pA;
            float zg = half ? pB : zB;
            float zo = half ? zB : pB;
            cst1 = sigm(zf) * cst1 + sigm(zi) * tanh_f(zg);
            float h1n = sigm(zo) * tanh_f(cst1);
            if (l < HH) h1b[l] = h1n;

            // ---- layer 1, part 1: wh1.h2 (overlaps the h1 allgather) ----
            float bA0 = bias1A, bA1 = 0.f, bA2 = 0.f, bA3 = 0.f;
            float bB0 = bias1B, bB1 = 0.f, bB2 = 0.f, bB3 = 0.f;
#pragma unroll
            for (int k2 = 0; k2 < 8; ++k2) {
                f4 g2 = h2r[k2];
                bA0 = fmaf((float)wh1A[k2].x, g2.x, bA0);
                bA1 = fmaf((float)wh1A[k2].y, g2.y, bA1);
                bA2 = fmaf((float)wh1A[k2].z, g2.z, bA2);
                bA3 = fmaf((float)wh1A[k2].w, g2.w, bA3);
                bB0 = fmaf((float)wh1B[k2].x, g2.x, bB0);
                bB1 = fmaf((float)wh1B[k2].y, g2.y, bB1);
                bB2 = fmaf((float)wh1B[k2].z, g2.z, bB2);
                bB3 = fmaf((float)wh1B[k2].w, g2.w, bB3);
            }
            // h1 allgather (broadcast reads, conflict-free)
#pragma unroll
            for (int k2 = 0; k2 < 8; ++k2) h1r[k2] = ((const f4*)h1b)[k2];
            // ---- layer 1, part 2: wi1.h1' ----
#pragma unroll
            for (int k2 = 0; k2 < 8; ++k2) {
                f4 h = h1r[k2];
                bA0 = fmaf((float)wi1A[k2].x, h.x, bA0);
                bA1 = fmaf((float)wi1A[k2].y, h.y, bA1);
                bA2 = fmaf((float)wi1A[k2].z, h.z, bA2);
                bA3 = fmaf((float)wi1A[k2].w, h.w, bA3);
                bB0 = fmaf((float)wi1B[k2].x, h.x, bB0);
                bB1 = fmaf((float)wi1B[k2].y, h.y, bB1);
                bB2 = fmaf((float)wi1B[k2].z, h.z, bB2);
                bB3 = fmaf((float)wi1B[k2].w, h.w, bB3);
            }
            zA = (bA0 + bA1) + (bA2 + bA3);
            zB = (bB0 + bB1) + (bB2 + bB3);
            pA = __shfl_xor(zA, 32, 64);
            pB = __shfl_xor(zB, 32, 64);
            zi = half ? pA : zA;
            zf = half ? zA : pA;
            zg = half ? pB : zB;
            zo = half ? zB : pB;
            cst2 = sigm(zf) * cst2 + sigm(zi) * tanh_f(zg);
            float h2n = sigm(zo) * tanh_f(cst2);
            if (l < HH) h2b[l] = h2n;
#pragma unroll
            for (int k2 = 0; k2 < 8; ++k2) h2r[k2] = ((const f4*)h2b)[k2];

            // ---- q_c = blc + wlin_c . h2 (redundant per 16-lane group) ----
            float s0 = blc, s1 = 0.f, s2 = 0.f, s3 = 0.f;
#pragma unroll
            for (int k2 = 0; k2 < 8; ++k2) {
                f4 h = h2r[k2];
                s0 = fmaf((float)wlc[k2].x, h.x, s0);
                s1 = fmaf((float)wlc[k2].y, h.y, s1);
                s2 = fmaf((float)wlc[k2].z, h.z, s2);
                s3 = fmaf((float)wlc[k2].w, h.w, s3);
            }
            float qown = (s0 + s1) + (s2 + s3);
            float t1 = __shfl_xor(qown, 16, 64);
            float t2 = __shfl_xor(qown, 32, 64);
            float t3 = __shfl_xor(t1, 32, 64);
            float q0 = (c == 0) ? qown : (c == 1) ? t1 : (c == 2) ? t2 : t3;
            float q1 = (c == 0) ? t1 : (c == 1) ? qown : (c == 2) ? t3 : t2;
            float q2 = (c == 0) ? t2 : (c == 1) ? t3 : (c == 2) ? qown : t1;
            float q3 = (c == 0) ? t3 : (c == 1) ? t2 : (c == 2) ? t1 : qown;
            float l0  = (q0 + gtc.x) * inv_tau;
            float l1_ = (q1 + gtc.y) * inv_tau;
            float l2  = (q2 + gtc.z) * inv_tau;
            float l3  = (q3 + gtc.w) * inv_tau;
            float m = fmaxf(fmaxf(l0, l1_), fmaxf(l2, l3));
            float e0 = __expf(l0 - m), e1 = __expf(l1_ - m);
            float e2 = __expf(l2 - m), e3 = __expf(l3 - m);
            float inv = rcpf((e0 + e1) + (e2 + e3));
            y0 = e0 * inv; y1 = e1 * inv; y2 = e2 * inv; y3 = e3 * inv;

            if (l == 0)
                *(float4*)(ob + (size_t)(t0 + k * TILE + s) * CC) =
                    make_float4(y0, y1, y2, y3);

            // ---- weight pins at loop END (values "redefined" per step: no remat) ----
            asm volatile("" : "+v"(wh0A[0]), "+v"(wh0A[1]), "+v"(wh0A[2]), "+v"(wh0A[3]),
                              "+v"(wh0A[4]), "+v"(wh0A[5]), "+v"(wh0A[6]), "+v"(wh0A[7]),
                              "+v"(wh0B[0]), "+v"(wh0B[1]), "+v"(wh0B[2]), "+v"(wh0B[3]),
                              "+v"(wh0B[4]), "+v"(wh0B[5]), "+v"(wh0B[6]), "+v"(wh0B[7]));
            asm volatile("" : "+v"(wi1A[0]), "+v"(wi1A[1]), "+v"(wi1A[2]), "+v"(wi1A[3]),
                              "+v"(wi1A[4]), "+v"(wi1A[5]), "+v"(wi1A[6]), "+v"(wi1A[7]),
                              "+v"(wi1B[0]), "+v"(wi1B[1]), "+v"(wi1B[2]), "+v"(wi1B[3]),
                              "+v"(wi1B[4]), "+v"(wi1B[5]), "+v"(wi1B[6]), "+v"(wi1B[7]));
            asm volatile("" : "+v"(wh1A[0]), "+v"(wh1A[1]), "+v"(wh1A[2]), "+v"(wh1A[3]),
                              "+v"(wh1A[4]), "+v"(wh1A[5]), "+v"(wh1A[6]), "+v"(wh1A[7]),
                              "+v"(wh1B[0]), "+v"(wh1B[1]), "+v"(wh1B[2]), "+v"(wh1B[3]),
                              "+v"(wh1B[4]), "+v"(wh1B[5]), "+v"(wh1B[6]), "+v"(wh1B[7]));
            asm volatile("" : "+v"(wlc[0]), "+v"(wlc[1]), "+v"(wlc[2]), "+v"(wlc[3]),
                              "+v"(wlc[4]), "+v"(wlc[5]), "+v"(wlc[6]), "+v"(wlc[7]),
                              "+v"(wctA), "+v"(wctB));
        }

        // ---- commit staged tile k+1 into the other buffer (vmcnt wait lands
        // here with a full tile of slack; single wave -> no barrier needed) ----
#pragma unroll
        for (int i = 0; i < 8; ++i)
            ((f4*)&zbuf[nb][0][0])[i * 64 + l] = sz[i];
        if (l < 16) gbuf[nb][l] = gv;
    }

    // ---- state save ----
    if (l < HH) {
        st[l] = h1b[l]; st[64 + l] = h2b[l];
        st[32 + l] = cst1;
        st[96 + l] = cst2;
    }
    if (l == 0) { st[128] = y0; st[129] = y1; st[130] = y2; st[131] = y3; }
}

// ---------------- Fallback (verbatim R3 kernel, used only if ws too small) ----------
extern "C" __global__ void __launch_bounds__(128, 2)
lstm_opt_enc(const float* __restrict__ states, const float* __restrict__ taup,
             const float* __restrict__ gumbel, const float* __restrict__ w_ih0,
             const float* __restrict__ w_hh0, const float* __restrict__ b_ih0,
             const float* __restrict__ b_hh0, const float* __restrict__ w_ih1,
             const float* __restrict__ w_hh1, const float* __restrict__ b_ih1,
             const float* __restrict__ b_hh1, const float* __restrict__ w_lin,
             const float* __restrict__ b_lin, float* __restrict__ out)
{
    const int b   = blockIdx.x;
    const int tid = threadIdx.x;
    const int l   = tid & 63;
    const int wv  = tid >> 6;
    const int u0  = l & 15;
    const int g   = l >> 4;
    const int u   = wv * 16 + u0;
    const int r   = g * 32 + u;

    __shared__ __align__(16) float xb[2][DD];
    __shared__ __align__(16) float h1b[2][HH];
    __shared__ __align__(16) float h2b[2][HH];

    float wi0r[68], wh0r[HH], wi1r[HH], wh1r[HH];
#pragma unroll
    for (int k = 0; k < 68; ++k) wi0r[k] = w_ih0[r * 68 + k];
#pragma unroll
    for (int k = 0; k < HH; ++k) wh0r[k] = w_hh0[r * HH + k];
#pragma unroll
    for (int k = 0; k < HH; ++k) wi1r[k] = w_ih1[r * HH + k];
#pragma unroll
    for (int k = 0; k < HH; ++k) wh1r[k] = w_hh1[r * HH + k];
    const float bias0 = b_ih0[r] + b_hh0[r];
    const float bias1 = b_ih1[r] + b_hh1[r];
    const float inv_tau = rcpf(taup[0]);
    const float wl0 = w_lin[g * HH + u0];
    const float wl1 = w_lin[g * HH + u0 + 16];
    const float blc = b_lin[g];

    float cst1 = 0.f, cst2 = 0.f;
    float y0 = 1.f, y1 = 0.f, y2 = 0.f, y3 = 0.f;

    const float* __restrict__ sb = states + (size_t)b * TT * DD;
    float* __restrict__ ob = out + (size_t)b * TT * CC;

    float xr = 0.f;
    if (tid < DD) xr = sb[tid];
    if (tid < HH) { h1b[0][tid] = 0.f; h2b[0][tid] = 0.f; }
    if (tid < DD) { xb[0][tid] = xr; xr = sb[DD + tid]; }
    __syncthreads();

    for (int t = 0; t < TT; ++t) {
        const int p = t & 1, np = p ^ 1;
        if (tid < DD) { xb[np][tid] = xr; }
        const int tn = (t + 2 < TT) ? t + 2 : TT - 1;
        if (tid < DD) { xr = sb[tn * DD + tid]; }
        const float4 gt = *(const float4*)(gumbel + ((size_t)t * BB + b) * CC);

        float a0 = bias0, a1 = 0.f, a2 = 0.f, a3 = 0.f;
        const float4* xv = (const float4*)xb[p];
#pragma unroll
        for (int k = 0; k < 16; ++k) {
            float4 x4 = xv[k];
            a0 = fmaf(wi0r[4 * k + 0], x4.x, a0);
            a1 = fmaf(wi0r[4 * k + 1], x4.y, a1);
            a2 = fmaf(wi0r[4 * k + 2], x4.z, a2);
            a3 = fmaf(wi0r[4 * k + 3], x4.w, a3);
        }
        a0 = fmaf(wi0r[64], y0, a0);
        a1 = fmaf(wi0r[65], y1, a1);
        a2 = fmaf(wi0r[66], y2, a2);
        a3 = fmaf(wi0r[67], y3, a3);
        const float4* h1v = (const float4*)h1b[p];
#pragma unroll
        for (int k = 0; k < 8; ++k) {
            float4 h4 = h1v[k];
            a0 = fmaf(wh0r[4 * k + 0], h4.x, a0);
            a1 = fmaf(wh0r[4 * k + 1], h4.y, a1);
            a2 = fmaf(wh0r[4 * k + 2], h4.z, a2);
            a3 = fmaf(wh0r[4 * k + 3], h4.w, a3);
        }
        float z = (a0 + a1) + (a2 + a3);
        float v1  = __shfl_xor(z, 16, 64);
        float lo  = (g & 1) ? v1 : z;
        float hi  = (g & 1) ? z  : v1;
        float lo2 = __shfl_xor(lo, 32, 64);
        float hi2 = __shfl_xor(hi, 32, 64);
        float zi = (g < 2) ? lo  : lo2;
        float zf = (g < 2) ? hi  : hi2;
        float zg = (g < 2) ? lo2 : lo;
        float zo = (g < 2) ? hi2 : hi;
        cst1 = sigm(zf) * cst1 + sigm(zi) * tanh_f(zg);
        float h1new = sigm(zo) * tanh_f(cst1);
        if (g == 0) h1b[np][u] = h1new;
        __syncthreads();

        a0 = bias1; a1 = 0.f; a2 = 0.f; a3 = 0.f;
        const float4* h1n = (const float4*)h1b[np];
        const float4* h2v = (const float4*)h2b[p];
#pragma unroll
        for (int k = 0; k < 8; ++k) {
            float4 h4 = h1n[k];
            float4 g4 = h2v[k];
            a0 = fmaf(wi1r[4 * k + 0], h4.x, a0);
            a1 = fmaf(wi1r[4 * k + 1], h4.y, a1);
            a2 = fmaf(wi1r[4 * k + 2], h4.z, a2);
            a3 = fmaf(wi1r[4 * k + 3], h4.w, a3);
            a0 = fmaf(wh1r[4 * k + 0], g4.x, a0);
            a1 = fmaf(wh1r[4 * k + 1], g4.y, a1);
            a2 = fmaf(wh1r[4 * k + 2], g4.z, a2);
            a3 = fmaf(wh1r[4 * k + 3], g4.w, a3);
        }
        z = (a0 + a1) + (a2 + a3);
        v1  = __shfl_xor(z, 16, 64);
        lo  = (g & 1) ? v1 : z;
        hi  = (g & 1) ? z  : v1;
        lo2 = __shfl_xor(lo, 32, 64);
        hi2 = __shfl_xor(hi, 32, 64);
        zi = (g < 2) ? lo  : lo2;
        zf = (g < 2) ? hi  : hi2;
        zg = (g < 2) ? lo2 : lo;
        zo = (g < 2) ? hi2 : hi;
        cst2 = sigm(zf) * cst2 + sigm(zi) * tanh_f(zg);
        float h2new = sigm(zo) * tanh_f(cst2);
        if (g == 0) h2b[np][u] = h2new;
        __syncthreads();

        float part = wl0 * h2b[np][u0] + wl1 * h2b[np][u0 + 16];
        part += __shfl_xor(part, 1, 64);
        part += __shfl_xor(part, 2, 64);
        part += __shfl_xor(part, 4, 64);
        part += __shfl_xor(part, 8, 64);
        float qown = part + blc;
        float t1 = __shfl_xor(qown, 16, 64);
        float t2 = __shfl_xor(qown, 32, 64);
        float t3 = __shfl_xor(t1, 32, 64);
        float q0 = (g == 0) ? qown : (g == 1) ? t1 : (g == 2) ? t2 : t3;
        float q1 = (g == 0) ? t1 : (g == 1) ? qown : (g == 2) ? t3 : t2;
        float q2 = (g == 0) ? t2 : (g == 1) ? t3 : (g == 2) ? qown : t1;
        float q3 = (g == 0) ? t3 : (g == 1) ? t2 : (g == 2) ? t1 : qown;
        float l0  = (q0 + gt.x) * inv_tau;
        float l1_ = (q1 + gt.y) * inv_tau;
        float l2  = (q2 + gt.z) * inv_tau;
        float l3  = (q3 + gt.w) * inv_tau;
        float m = fmaxf(fmaxf(l0, l1_), fmaxf(l2, l3));
        float e0 = __expf(l0 - m), e1 = __expf(l1_ - m);
        float e2 = __expf(l2 - m), e3 = __expf(l3 - m);
        float inv = rcpf((e0 + e1) + (e2 + e3));
        y0 = e0 * inv; y1 = e1 * inv; y2 = e2 * inv; y3 = e3 * inv;

        if (tid == 0) *(float4*)(ob + (size_t)t * CC) = make_float4(y0, y1, y2, y3);
    }
}

extern "C" void kernel_launch(void* const* d_in, const int* in_sizes, int n_in,
                              void* d_out, int out_size, void* d_ws, size_t ws_size,
                              hipStream_t stream) {
    const float* states = (const float*)d_in[0];
    const float* tau    = (const float*)d_in[1];
    const float* gumbel = (const float*)d_in[2];
    const float* w_ih0  = (const float*)d_in[3];
    const float* w_hh0  = (const float*)d_in[4];
    const float* b_ih0  = (const float*)d_in[5];
    const float* b_hh0  = (const float*)d_in[6];
    const float* w_ih1  = (const float*)d_in[7];
    const float* w_hh1  = (const float*)d_in[8];
    const float* b_ih1  = (const float*)d_in[9];
    const float* b_hh1  = (const float*)d_in[10];
    const float* w_lin  = (const float*)d_in[11];
    const float* b_lin  = (const float*)d_in[12];
    float* out = (float*)d_out;

    // workspace: zx chunk [B][Tc][128] f32 + carry state [B][136] f32
    const long long state_bytes = (long long)BB * 136 * 4;
    long long avail = (long long)ws_size - state_bytes;
    long long Tcl = avail > 0 ? avail / ((long long)BB * 128 * 4) : 0;
    int Tc = (int)(Tcl > TT ? TT : Tcl);
    Tc &= ~(TILE - 1);                       // tiles of 16 timesteps

    if (Tc < TILE) {
        hipLaunchKernelGGL(lstm_opt_enc, dim3(BB), dim3(128), 0, stream,
                           states, tau, gumbel, w_ih0, w_hh0, b_ih0, b_hh0,
                           w_ih1, w_hh1, b_ih1, b_hh1, w_lin, b_lin, out);
        return;
    }

    float* zx = (float*)d_ws;
    float* st = (float*)((char*)d_ws + (size_t)BB * Tc * 128 * 4);

    int done = 0, first = 1;
    while (done < TT) {
        int tc = (TT - done < Tc) ? (TT - done) : Tc;
        int tiles = (tc + 15) / 16;
        hipLaunchKernelGGL(zx_gemm, dim3(tiles, BB), dim3(128), 0, stream,
                           states, w_ih0, b_ih0, b_hh0, zx, done, tc, Tc);
        hipLaunchKernelGGL(lstm_rec1w, dim3(BB), dim3(64), 0, stream,
                           zx, tau, gumbel, w_ih0, w_hh0, w_ih1, w_hh1,
                           b_ih1, b_hh1, w_lin, b_lin, out, st, done, tc, Tc, first);
        first = 0;
        done += tc;
    }
}

// Round 8
// 1336.814 us; speedup vs baseline: 1.6261x; 1.0386x over previous
//
#include <hip/hip_runtime.h>

#define BB 512
#define TT 1024
#define DD 64
#define HH 32
#define CC 4
#define TILE 16
#define NT (TT / TILE)

typedef float f4 __attribute__((ext_vector_type(4)));
typedef _Float16 h4 __attribute__((ext_vector_type(4)));

__device__ __forceinline__ float rcpf(float x) { return __builtin_amdgcn_rcpf(x); }
__device__ __forceinline__ float sigm(float x) { return rcpf(1.0f + __expf(-x)); }
__device__ __forceinline__ float tanh_f(float x) {
    return 1.0f - 2.0f * rcpf(__expf(2.0f * x) + 1.0f);
}
__device__ __forceinline__ h4 cvt_h4(f4 a) {
    h4 w;
    w.x = (_Float16)a.x; w.y = (_Float16)a.y;
    w.z = (_Float16)a.z; w.w = (_Float16)a.w;
    return w;
}

// 8x f4 dot-accumulate with f16 weight vector (compiler emits v_fma_mix)
#define DOT8(a0, a1, a2, a3, W, H)                      \
    _Pragma("unroll")                                   \
    for (int k2 = 0; k2 < 8; ++k2) {                    \
        f4 h_ = H[k2];                                  \
        a0 = fmaf((float)W[k2].x, h_.x, a0);            \
        a1 = fmaf((float)W[k2].y, h_.y, a1);            \
        a2 = fmaf((float)W[k2].z, h_.z, a2);            \
        a3 = fmaf((float)W[k2].w, h_.w, a3);            \
    }

// gate combine: lane l owns rows rA=l (i|f) and rB=l+64 (g|o); one xor-32 pair
#define COMBINE(zA, zB, zi, zf, zg, zo)                 \
    {                                                   \
        float pA_ = __shfl_xor(zA, 32, 64);             \
        float pB_ = __shfl_xor(zB, 32, 64);             \
        zi = half ? pA_ : zA; zf = half ? zA : pA_;     \
        zg = half ? pB_ : zB; zo = half ? zB : pB_;     \
    }

// ---------------- Kernel 1: zx[b,t,r] = bias0[r] + sum_k x[b,t,k]*w_ih0[r,k] ----------
__global__ void __launch_bounds__(128, 4)
zx_gemm(const float* __restrict__ states,  // [B,T,64]
        const float* __restrict__ w_ih0,   // [128,68]
        const float* __restrict__ b_ih0,
        const float* __restrict__ b_hh0,
        float* __restrict__ zx)            // [B,T,128]
{
    const int b = blockIdx.y;
    const int tile = blockIdx.x;
    const int tid = threadIdx.x;
    __shared__ __align__(16) float xs[16][DD];

    const int tbase = tile * 16;
#pragma unroll
    for (int i = 0; i < 2; ++i) {
        int f = i * 128 + tid;           // float4 id 0..255
        int row = f >> 4, c4 = f & 15;
        int t = tbase + row; if (t > TT - 1) t = TT - 1;
        ((f4*)xs)[f] = *(const f4*)(states + ((size_t)b * TT + t) * DD + c4 * 4);
    }
    __syncthreads();

    const int r = tid;
    const f4* wr = (const f4*)(w_ih0 + (size_t)r * 68);
    f4 w[16];
#pragma unroll
    for (int k = 0; k < 16; ++k) w[k] = wr[k];
    const float bias = b_ih0[r] + b_hh0[r];

    for (int i = 0; i < 16; ++i) {
        int t = tbase + i;
        if (t >= TT) break;
        const f4* xv = (const f4*)xs[i];
        float a0 = bias, a1 = 0.f, a2 = 0.f, a3 = 0.f;
#pragma unroll
        for (int k = 0; k < 16; ++k) {
            f4 x4 = xv[k];
            a0 = fmaf(w[k].x, x4.x, a0);
            a1 = fmaf(w[k].y, x4.y, a1);
            a2 = fmaf(w[k].z, x4.z, a2);
            a3 = fmaf(w[k].w, x4.w, a3);
        }
        zx[((size_t)b * TT + t) * 128 + r] = (a0 + a1) + (a2 + a3);
    }
}

// ---------------- Kernel 2: re-pipelined single-wave recurrence ----------------
// Spine per step t: q(t) -> softmax -> L0-tail -> h1(t+1) -> L1 -> h2(t+1).
// L0(t+1)'s main dot (wh0*h1(t)) issues BEFORE q/softmax(t) (independent),
// hiding the h2-allgather; h1-allgather hides under L1's wh1*h2 dot; the
// q permutation is 3 PARALLEL xor-shuffles (16/32/48). zx is consumed one
// step ahead (row t+1), so zbuf tiles are staged with a +1 row shift.
__global__ void __launch_bounds__(64, 1)
lstm_pipe(const float* __restrict__ zx,      // [B,TT,128]
          const float* __restrict__ taup,
          const float* __restrict__ gumbel,  // [T,B,1,C]
          const float* __restrict__ w_ih0,   // [128,68] (ct cols 64..67)
          const float* __restrict__ w_hh0,   // [128,32]
          const float* __restrict__ w_ih1,   // [128,32]
          const float* __restrict__ w_hh1,   // [128,32]
          const float* __restrict__ b_ih1,
          const float* __restrict__ b_hh1,
          const float* __restrict__ w_lin,   // [4,32]
          const float* __restrict__ b_lin,   // [4]
          float* __restrict__ out)           // [B,T,4]
{
    const int b    = blockIdx.x;
    const int l    = threadIdx.x;     // 0..63
    const int half = l >> 5;
    const int rA   = l;               // rows l (i|f) and l+64 (g|o)
    const int rB   = l + 64;
    const int c    = l >> 4;          // q channel group

    __shared__ __align__(16) float zbuf[2][TILE][128];   // 16 KB, +1-shifted rows
    __shared__ __align__(16) float4 gbuf[2][TILE];
    __shared__ __align__(16) float h1b[HH];
    __shared__ __align__(16) float h2b[HH];

    // ---- per-lane weights: f32 wct, f16 the rest (fit + stay resident) ----
    f4 wctA = *(const f4*)(w_ih0 + (size_t)rA * 68 + 64);
    f4 wctB = *(const f4*)(w_ih0 + (size_t)rB * 68 + 64);
    h4 wh0A[8], wh0B[8], wi1A[8], wi1B[8], wh1A[8], wh1B[8], wlc[8];
#pragma unroll
    for (int k = 0; k < 8; ++k) {
        wh0A[k] = cvt_h4(*(const f4*)(w_hh0 + (size_t)rA * HH + 4 * k));
        wh0B[k] = cvt_h4(*(const f4*)(w_hh0 + (size_t)rB * HH + 4 * k));
        wi1A[k] = cvt_h4(*(const f4*)(w_ih1 + (size_t)rA * HH + 4 * k));
        wi1B[k] = cvt_h4(*(const f4*)(w_ih1 + (size_t)rB * HH + 4 * k));
        wh1A[k] = cvt_h4(*(const f4*)(w_hh1 + (size_t)rA * HH + 4 * k));
        wh1B[k] = cvt_h4(*(const f4*)(w_hh1 + (size_t)rB * HH + 4 * k));
        wlc[k]  = cvt_h4(*(const f4*)(w_lin + (size_t)c * HH + 4 * k));
    }
    const float bias1A = b_ih1[rA] + b_hh1[rA];
    const float bias1B = b_ih1[rB] + b_hh1[rB];
    const float inv_tau = rcpf(taup[0]);
    const float blc = b_lin[c];

    const float* __restrict__ zb = zx + (size_t)b * TT * 128;
    float* __restrict__ ob = out + (size_t)b * TT * CC;
    const int srow = l >> 5;          // staging: f4 slot f=i*64+l -> row i*2+srow, col4 l&31
    const int scol = l & 31;

    // ---- stage tile 0: zx rows 1..16, gumbel t=0..15 ----
    {
        f4 sz[8];
#pragma unroll
        for (int i = 0; i < 8; ++i) {
            int row = 1 + i * 2 + srow;
            sz[i] = *(const f4*)(zb + (size_t)row * 128 + scol * 4);
        }
        float4 gv = *(const float4*)(gumbel + ((size_t)(l & 15) * BB + b) * CC);
#pragma unroll
        for (int i = 0; i < 8; ++i) ((f4*)&zbuf[0][0][0])[i * 64 + l] = sz[i];
        if (l < 16) gbuf[0][l] = gv;
    }

    float cst1 = 0.f, cst2 = 0.f;
    f4 h1r[8];

    // ---- prologue: h1(0), h2(0) (c/h init 0, ct0 = one-hot(0)) ----
    {
        float zA = zb[rA] + wctA.x;            // zx(0) already holds bias0
        float zB = zb[rB] + wctB.x;
        float zi, zf, zg, zo;
        COMBINE(zA, zB, zi, zf, zg, zo);
        (void)zf;
        cst1 = sigm(zi) * tanh_f(zg);          // sigm(zf)*0 dropped (exact)
        float h1n = sigm(zo) * tanh_f(cst1);
        if (l < HH) h1b[l] = h1n;
#pragma unroll
        for (int k2 = 0; k2 < 8; ++k2) h1r[k2] = ((const f4*)h1b)[k2];

        float bA0 = bias1A, bA1 = 0.f, bA2 = 0.f, bA3 = 0.f;
        float bB0 = bias1B, bB1 = 0.f, bB2 = 0.f, bB3 = 0.f;
        DOT8(bA0, bA1, bA2, bA3, wi1A, h1r);
        DOT8(bB0, bB1, bB2, bB3, wi1B, h1r);
        zA = (bA0 + bA1) + (bA2 + bA3);
        zB = (bB0 + bB1) + (bB2 + bB3);
        COMBINE(zA, zB, zi, zf, zg, zo);
        cst2 = sigm(zi) * tanh_f(zg);
        float h2n = sigm(zo) * tanh_f(cst2);
        if (l < HH) h2b[l] = h2n;
    }

    // ---- main loop: tiles of 16 steps, staging split in 8-step halves ----
    for (int k = 0; k < NT; ++k) {
        const int cb = k & 1, nb = cb ^ 1;
        const int kn = (k + 1 < NT) ? k + 1 : 0;   // harmless reload at the end
        float4 gv;

#pragma unroll
        for (int hf = 0; hf < 2; ++hf) {
            // issue staging loads for next-tile rows hf*8 .. hf*8+7 (4 f4/lane)
            f4 szh[4];
#pragma unroll
            for (int i = 0; i < 4; ++i) {
                int ii = hf * 4 + i;
                int row = kn * TILE + 1 + ii * 2 + srow;
                if (row > TT - 1) row = TT - 1;
                szh[i] = *(const f4*)(zb + (size_t)row * 128 + scol * 4);
            }
            if (hf == 0)
                gv = *(const float4*)(gumbel +
                        ((size_t)(kn * TILE + (l & 15)) * BB + b) * CC);

#pragma unroll 2
            for (int s8 = 0; s8 < 8; ++s8) {
                const int s = hf * 8 + s8;
                const int t = k * TILE + s;

                // (1) early LDS issues: zx(t+1), gumbel(t), h2(t) allgather
                const float zxnA = zbuf[cb][s][rA];
                const float zxnB = zbuf[cb][s][rB];
                const float4 gtc = gbuf[cb][s];
                f4 h2g[8];
#pragma unroll
                for (int k2 = 0; k2 < 8; ++k2) h2g[k2] = ((const f4*)h2b)[k2];

                // (2) L0(t+1) main dot: wh0 . h1(t)  (hides (1) latency)
                float aA0 = 0.f, aA1 = 0.f, aA2 = 0.f, aA3 = 0.f;
                float aB0 = 0.f, aB1 = 0.f, aB2 = 0.f, aB3 = 0.f;
                DOT8(aA0, aA1, aA2, aA3, wh0A, h1r);
                DOT8(aB0, aB1, aB2, aB3, wh0B, h1r);

                // (3) q(t) = blc + wlc . h2(t)
                float s0 = blc, s1 = 0.f, s2 = 0.f, s3 = 0.f;
                DOT8(s0, s1, s2, s3, wlc, h2g);
                float qown = (s0 + s1) + (s2 + s3);

                // (4) 3 PARALLEL perms + softmax((q+g)/tau) -> y(t)
                float t1 = __shfl_xor(qown, 16, 64);
                float t2 = __shfl_xor(qown, 32, 64);
                float t3 = __shfl_xor(qown, 48, 64);
                float q0 = (c == 0) ? qown : (c == 1) ? t1 : (c == 2) ? t2 : t3;
                float q1 = (c == 0) ? t1 : (c == 1) ? qown : (c == 2) ? t3 : t2;
                float q2 = (c == 0) ? t2 : (c == 1) ? t3 : (c == 2) ? qown : t1;
                float q3 = (c == 0) ? t3 : (c == 1) ? t2 : (c == 2) ? t1 : qown;
                float l0  = (q0 + gtc.x) * inv_tau;
                float l1_ = (q1 + gtc.y) * inv_tau;
                float l2  = (q2 + gtc.z) * inv_tau;
                float l3  = (q3 + gtc.w) * inv_tau;
                float m = fmaxf(fmaxf(l0, l1_), fmaxf(l2, l3));
                float e0 = __expf(l0 - m), e1 = __expf(l1_ - m);
                float e2 = __expf(l2 - m), e3 = __expf(l3 - m);
                float inv = rcpf((e0 + e1) + (e2 + e3));
                float y0 = e0 * inv, y1 = e1 * inv, y2 = e2 * inv, y3 = e3 * inv;
                if (l == 0)
                    *(float4*)(ob + (size_t)t * CC) = make_float4(y0, y1, y2, y3);

                // (5) L0 tail: + zx(t+1) + wct.y(t); combine; act -> h1(t+1)
                aA0 += zxnA; aB0 += zxnB;
                aA0 = fmaf(wctA.x, y0, aA0); aA1 = fmaf(wctA.y, y1, aA1);
                aA2 = fmaf(wctA.z, y2, aA2); aA3 = fmaf(wctA.w, y3, aA3);
                aB0 = fmaf(wctB.x, y0, aB0); aB1 = fmaf(wctB.y, y1, aB1);
                aB2 = fmaf(wctB.z, y2, aB2); aB3 = fmaf(wctB.w, y3, aB3);
                float zA = (aA0 + aA1) + (aA2 + aA3);
                float zB = (aB0 + aB1) + (aB2 + aB3);
                float zi, zf, zg, zo;
                COMBINE(zA, zB, zi, zf, zg, zo);
                cst1 = sigm(zf) * cst1 + sigm(zi) * tanh_f(zg);
                float h1n = sigm(zo) * tanh_f(cst1);
                if (l < HH) h1b[l] = h1n;

                // (6) h1(t+1) allgather (hidden by (7)'s wh1 dot)
#pragma unroll
                for (int k2 = 0; k2 < 8; ++k2) h1r[k2] = ((const f4*)h1b)[k2];

                // (7) L1(t+1): wh1 . h2(t) first, then wi1 . h1(t+1)
                float bA0 = bias1A, bA1 = 0.f, bA2 = 0.f, bA3 = 0.f;
                float bB0 = bias1B, bB1 = 0.f, bB2 = 0.f, bB3 = 0.f;
                DOT8(bA0, bA1, bA2, bA3, wh1A, h2g);
                DOT8(bB0, bB1, bB2, bB3, wh1B, h2g);
                DOT8(bA0, bA1, bA2, bA3, wi1A, h1r);
                DOT8(bB0, bB1, bB2, bB3, wi1B, h1r);
                zA = (bA0 + bA1) + (bA2 + bA3);
                zB = (bB0 + bB1) + (bB2 + bB3);
                COMBINE(zA, zB, zi, zf, zg, zo);
                cst2 = sigm(zf) * cst2 + sigm(zi) * tanh_f(zg);
                float h2n = sigm(zo) * tanh_f(cst2);
                if (l < HH) h2b[l] = h2n;
            }

            // commit this half's staged rows (>=8 steps of vmcnt slack)
#pragma unroll
            for (int i = 0; i < 4; ++i)
                ((f4*)&zbuf[nb][0][0])[(hf * 4 + i) * 64 + l] = szh[i];
        }
        if (l < 16) gbuf[nb][l] = gv;

        // ---- weight pins ONCE PER TILE: keep resident without per-step
        // scheduling fences (VGPR_Count < ~170 in counters => remat returned)
        asm volatile("" : "+v"(wh0A[0]), "+v"(wh0A[1]), "+v"(wh0A[2]), "+v"(wh0A[3]),
                          "+v"(wh0A[4]), "+v"(wh0A[5]), "+v"(wh0A[6]), "+v"(wh0A[7]),
                          "+v"(wh0B[0]), "+v"(wh0B[1]), "+v"(wh0B[2]), "+v"(wh0B[3]),
                          "+v"(wh0B[4]), "+v"(wh0B[5]), "+v"(wh0B[6]), "+v"(wh0B[7]));
        asm volatile("" : "+v"(wi1A[0]), "+v"(wi1A[1]), "+v"(wi1A[2]), "+v"(wi1A[3]),
                          "+v"(wi1A[4]), "+v"(wi1A[5]), "+v"(wi1A[6]), "+v"(wi1A[7]),
                          "+v"(wi1B[0]), "+v"(wi1B[1]), "+v"(wi1B[2]), "+v"(wi1B[3]),
                          "+v"(wi1B[4]), "+v"(wi1B[5]), "+v"(wi1B[6]), "+v"(wi1B[7]));
        asm volatile("" : "+v"(wh1A[0]), "+v"(wh1A[1]), "+v"(wh1A[2]), "+v"(wh1A[3]),
                          "+v"(wh1A[4]), "+v"(wh1A[5]), "+v"(wh1A[6]), "+v"(wh1A[7]),
                          "+v"(wh1B[0]), "+v"(wh1B[1]), "+v"(wh1B[2]), "+v"(wh1B[3]),
                          "+v"(wh1B[4]), "+v"(wh1B[5]), "+v"(wh1B[6]), "+v"(wh1B[7]));
        asm volatile("" : "+v"(wlc[0]), "+v"(wlc[1]), "+v"(wlc[2]), "+v"(wlc[3]),
                          "+v"(wlc[4]), "+v"(wlc[5]), "+v"(wlc[6]), "+v"(wlc[7]),
                          "+v"(wctA), "+v"(wctB));
    }
}

// ---------------- Fallback (verbatim R3 kernel, used only if ws too small) ----------
extern "C" __global__ void __launch_bounds__(128, 2)
lstm_opt_enc(const float* __restrict__ states, const float* __restrict__ taup,
             const float* __restrict__ gumbel, const float* __restrict__ w_ih0,
             const float* __restrict__ w_hh0, const float* __restrict__ b_ih0,
             const float* __restrict__ b_hh0, const float* __restrict__ w_ih1,
             const float* __restrict__ w_hh1, const float* __restrict__ b_ih1,
             const float* __restrict__ b_hh1, const float* __restrict__ w_lin,
             const float* __restrict__ b_lin, float* __restrict__ out)
{
    const int b   = blockIdx.x;
    const int tid = threadIdx.x;
    const int l   = tid & 63;
    const int wv  = tid >> 6;
    const int u0  = l & 15;
    const int g   = l >> 4;
    const int u   = wv * 16 + u0;
    const int r   = g * 32 + u;

    __shared__ __align__(16) float xb[2][DD];
    __shared__ __align__(16) float h1b[2][HH];
    __shared__ __align__(16) float h2b[2][HH];

    float wi0r[68], wh0r[HH], wi1r[HH], wh1r[HH];
#pragma unroll
    for (int k = 0; k < 68; ++k) wi0r[k] = w_ih0[r * 68 + k];
#pragma unroll
    for (int k = 0; k < HH; ++k) wh0r[k] = w_hh0[r * HH + k];
#pragma unroll
    for (int k = 0; k < HH; ++k) wi1r[k] = w_ih1[r * HH + k];
#pragma unroll
    for (int k = 0; k < HH; ++k) wh1r[k] = w_hh1[r * HH + k];
    const float bias0 = b_ih0[r] + b_hh0[r];
    const float bias1 = b_ih1[r] + b_hh1[r];
    const float inv_tau = rcpf(taup[0]);
    const float wl0 = w_lin[g * HH + u0];
    const float wl1 = w_lin[g * HH + u0 + 16];
    const float blc = b_lin[g];

    float cst1 = 0.f, cst2 = 0.f;
    float y0 = 1.f, y1 = 0.f, y2 = 0.f, y3 = 0.f;

    const float* __restrict__ sb = states + (size_t)b * TT * DD;
    float* __restrict__ ob = out + (size_t)b * TT * CC;

    float xr = 0.f;
    if (tid < DD) xr = sb[tid];
    if (tid < HH) { h1b[0][tid] = 0.f; h2b[0][tid] = 0.f; }
    if (tid < DD) { xb[0][tid] = xr; xr = sb[DD + tid]; }
    __syncthreads();

    for (int t = 0; t < TT; ++t) {
        const int p = t & 1, np = p ^ 1;
        if (tid < DD) { xb[np][tid] = xr; }
        const int tn = (t + 2 < TT) ? t + 2 : TT - 1;
        if (tid < DD) { xr = sb[tn * DD + tid]; }
        const float4 gt = *(const float4*)(gumbel + ((size_t)t * BB + b) * CC);

        float a0 = bias0, a1 = 0.f, a2 = 0.f, a3 = 0.f;
        const float4* xv = (const float4*)xb[p];
#pragma unroll
        for (int k = 0; k < 16; ++k) {
            float4 x4 = xv[k];
            a0 = fmaf(wi0r[4 * k + 0], x4.x, a0);
            a1 = fmaf(wi0r[4 * k + 1], x4.y, a1);
            a2 = fmaf(wi0r[4 * k + 2], x4.z, a2);
            a3 = fmaf(wi0r[4 * k + 3], x4.w, a3);
        }
        a0 = fmaf(wi0r[64], y0, a0);
        a1 = fmaf(wi0r[65], y1, a1);
        a2 = fmaf(wi0r[66], y2, a2);
        a3 = fmaf(wi0r[67], y3, a3);
        const float4* h1v = (const float4*)h1b[p];
#pragma unroll
        for (int k = 0; k < 8; ++k) {
            float4 h4 = h1v[k];
            a0 = fmaf(wh0r[4 * k + 0], h4.x, a0);
            a1 = fmaf(wh0r[4 * k + 1], h4.y, a1);
            a2 = fmaf(wh0r[4 * k + 2], h4.z, a2);
            a3 = fmaf(wh0r[4 * k + 3], h4.w, a3);
        }
        float z = (a0 + a1) + (a2 + a3);
        float v1  = __shfl_xor(z, 16, 64);
        float lo  = (g & 1) ? v1 : z;
        float hi  = (g & 1) ? z  : v1;
        float lo2 = __shfl_xor(lo, 32, 64);
        float hi2 = __shfl_xor(hi, 32, 64);
        float zi = (g < 2) ? lo  : lo2;
        float zf = (g < 2) ? hi  : hi2;
        float zg = (g < 2) ? lo2 : lo;
        float zo = (g < 2) ? hi2 : hi;
        cst1 = sigm(zf) * cst1 + sigm(zi) * tanh_f(zg);
        float h1new = sigm(zo) * tanh_f(cst1);
        if (g == 0) h1b[np][u] = h1new;
        __syncthreads();

        a0 = bias1; a1 = 0.f; a2 = 0.f; a3 = 0.f;
        const float4* h1n = (const float4*)h1b[np];
        const float4* h2v = (const float4*)h2b[p];
#pragma unroll
        for (int k = 0; k < 8; ++k) {
            float4 h4 = h1n[k];
            float4 g4 = h2v[k];
            a0 = fmaf(wi1r[4 * k + 0], h4.x, a0);
            a1 = fmaf(wi1r[4 * k + 1], h4.y, a1);
            a2 = fmaf(wi1r[4 * k + 2], h4.z, a2);
            a3 = fmaf(wi1r[4 * k + 3], h4.w, a3);
            a0 = fmaf(wh1r[4 * k + 0], g4.x, a0);
            a1 = fmaf(wh1r[4 * k + 1], g4.y, a1);
            a2 = fmaf(wh1r[4 * k + 2], g4.z, a2);
            a3 = fmaf(wh1r[4 * k + 3], g4.w, a3);
        }
        z = (a0 + a1) + (a2 + a3);
        v1  = __shfl_xor(z, 16, 64);
        lo  = (g & 1) ? v1 : z;
        hi  = (g & 1) ? z  : v1;
        lo2 = __shfl_xor(lo, 32, 64);
        hi2 = __shfl_xor(hi, 32, 64);
        zi = (g < 2) ? lo  : lo2;
        zf = (g < 2) ? hi  : hi2;
        zg = (g < 2) ? lo2 : lo;
        zo = (g < 2) ? hi2 : hi;
        cst2 = sigm(zf) * cst2 + sigm(zi) * tanh_f(zg);
        float h2new = sigm(zo) * tanh_f(cst2);
        if (g == 0) h2b[np][u] = h2new;
        __syncthreads();

        float part = wl0 * h2b[np][u0] + wl1 * h2b[np][u0 + 16];
        part += __shfl_xor(part, 1, 64);
        part += __shfl_xor(part, 2, 64);
        part += __shfl_xor(part, 4, 64);
        part += __shfl_xor(part, 8, 64);
        float qown = part + blc;
        float t1 = __shfl_xor(qown, 16, 64);
        float t2 = __shfl_xor(qown, 32, 64);
        float t3 = __shfl_xor(t1, 32, 64);
        float q0 = (g == 0) ? qown : (g == 1) ? t1 : (g == 2) ? t2 : t3;
        float q1 = (g == 0) ? t1 : (g == 1) ? qown : (g == 2) ? t3 : t2;
        float q2 = (g == 0) ? t2 : (g == 1) ? t3 : (g == 2) ? qown : t1;
        float q3 = (g == 0) ? t3 : (g == 1) ? t2 : (g == 2) ? t1 : qown;
        float l0  = (q0 + gt.x) * inv_tau;
        float l1_ = (q1 + gt.y) * inv_tau;
        float l2  = (q2 + gt.z) * inv_tau;
        float l3  = (q3 + gt.w) * inv_tau;
        float m = fmaxf(fmaxf(l0, l1_), fmaxf(l2, l3));
        float e0 = __expf(l0 - m), e1 = __expf(l1_ - m);
        float e2 = __expf(l2 - m), e3 = __expf(l3 - m);
        float inv = rcpf((e0 + e1) + (e2 + e3));
        y0 = e0 * inv; y1 = e1 * inv; y2 = e2 * inv; y3 = e3 * inv;

        if (tid == 0) *(float4*)(ob + (size_t)t * CC) = make_float4(y0, y1, y2, y3);
    }
}

extern "C" void kernel_launch(void* const* d_in, const int* in_sizes, int n_in,
                              void* d_out, int out_size, void* d_ws, size_t ws_size,
                              hipStream_t stream) {
    const float* states = (const float*)d_in[0];
    const float* tau    = (const float*)d_in[1];
    const float* gumbel = (const float*)d_in[2];
    const float* w_ih0  = (const float*)d_in[3];
    const float* w_hh0  = (const float*)d_in[4];
    const float* b_ih0  = (const float*)d_in[5];
    const float* b_hh0  = (const float*)d_in[6];
    const float* w_ih1  = (const float*)d_in[7];
    const float* w_hh1  = (const float*)d_in[8];
    const float* b_ih1  = (const float*)d_in[9];
    const float* b_hh1  = (const float*)d_in[10];
    const float* w_lin  = (const float*)d_in[11];
    const float* b_lin  = (const float*)d_in[12];
    float* out = (float*)d_out;

    // need the full zx buffer [B][TT][128] f32 (empirically ws is big enough)
    const size_t zx_bytes = (size_t)BB * TT * 128 * 4;
    if (ws_size >= zx_bytes) {
        float* zx = (float*)d_ws;
        hipLaunchKernelGGL(zx_gemm, dim3(NT, BB), dim3(128), 0, stream,
                           states, w_ih0, b_ih0, b_hh0, zx);
        hipLaunchKernelGGL(lstm_pipe, dim3(BB), dim3(64), 0, stream,
                           zx, tau, gumbel, w_ih0, w_hh0, w_ih1, w_hh1,
                           b_ih1, b_hh1, w_lin, b_lin, out);
    } else {
        hipLaunchKernelGGL(lstm_opt_enc, dim3(BB), dim3(128), 0, stream,
                           states, tau, gumbel, w_ih0, w_hh0, b_ih0, b_hh0,
                           w_ih1, w_hh1, b_ih1, b_hh1, w_lin, b_lin, out);
    }
}

// Round 9
// 948.882 us; speedup vs baseline: 2.2909x; 1.4088x over previous
//
#include <hip/hip_runtime.h>

#define BB 512
#define TT 1024
#define DD 64
#define HH 32
#define CC 4
#define TILE 16
#define NT (TT / TILE)

typedef float f4 __attribute__((ext_vector_type(4)));
typedef _Float16 hv2 __attribute__((ext_vector_type(2)));

__device__ __forceinline__ float rcpf(float x) { return __builtin_amdgcn_rcpf(x); }
__device__ __forceinline__ float sigm(float x) { return rcpf(1.0f + __expf(-x)); }
__device__ __forceinline__ float tanh_f(float x) {
    return 1.0f - 2.0f * rcpf(__expf(2.0f * x) + 1.0f);
}
__device__ __forceinline__ float pk2(float a, float b) {
    hv2 t; t.x = (_Float16)a; t.y = (_Float16)b;
    return __builtin_bit_cast(float, t);
}
__device__ __forceinline__ hv2 bch(float x) { return __builtin_bit_cast(hv2, x); }
__device__ __forceinline__ float fdot2(float w, float h, float c) {
    return __builtin_amdgcn_fdot2(bch(w), bch(h), c, false);
}

// dot-32 via 16 v_dot2_f32_f16: W = float[16] (f16-pair bits), H4 = f4[4] raw f16x8
#define DOT32(a0, a1, a2, a3, W, H4)                    \
    _Pragma("unroll")                                   \
    for (int k2 = 0; k2 < 4; ++k2) {                    \
        f4 h_ = H4[k2];                                 \
        a0 = fdot2(W[4 * k2 + 0], h_.x, a0);            \
        a1 = fdot2(W[4 * k2 + 1], h_.y, a1);            \
        a2 = fdot2(W[4 * k2 + 2], h_.z, a2);            \
        a3 = fdot2(W[4 * k2 + 3], h_.w, a3);            \
    }

// gate combine: lane l owns rows rA=l (i|f) and rB=l+64 (g|o); one xor-32 pair
#define COMBINE(zA, zB, zi, zf, zg, zo)                 \
    {                                                   \
        float pA_ = __shfl_xor(zA, 32, 64);             \
        float pB_ = __shfl_xor(zB, 32, 64);             \
        zi = half ? pA_ : zA; zf = half ? zA : pA_;     \
        zg = half ? pB_ : zB; zo = half ? zB : pB_;     \
    }

// ---------------- Kernel 1: zx[b,t,r] = bias0[r] + sum_k x[b,t,k]*w_ih0[r,k] ----------
__global__ void __launch_bounds__(128, 4)
zx_gemm(const float* __restrict__ states,  // [B,T,64]
        const float* __restrict__ w_ih0,   // [128,68]
        const float* __restrict__ b_ih0,
        const float* __restrict__ b_hh0,
        float* __restrict__ zx)            // [B,T,128]
{
    const int b = blockIdx.y;
    const int tile = blockIdx.x;
    const int tid = threadIdx.x;
    __shared__ __align__(16) float xs[16][DD];

    const int tbase = tile * 16;
#pragma unroll
    for (int i = 0; i < 2; ++i) {
        int f = i * 128 + tid;           // float4 id 0..255
        int row = f >> 4, c4 = f & 15;
        int t = tbase + row; if (t > TT - 1) t = TT - 1;
        ((f4*)xs)[f] = *(const f4*)(states + ((size_t)b * TT + t) * DD + c4 * 4);
    }
    __syncthreads();

    const int r = tid;
    const f4* wr = (const f4*)(w_ih0 + (size_t)r * 68);
    f4 w[16];
#pragma unroll
    for (int k = 0; k < 16; ++k) w[k] = wr[k];
    const float bias = b_ih0[r] + b_hh0[r];

    for (int i = 0; i < 16; ++i) {
        int t = tbase + i;
        if (t >= TT) break;
        const f4* xv = (const f4*)xs[i];
        float a0 = bias, a1 = 0.f, a2 = 0.f, a3 = 0.f;
#pragma unroll
        for (int k = 0; k < 16; ++k) {
            f4 x4 = xv[k];
            a0 = fmaf(w[k].x, x4.x, a0);
            a1 = fmaf(w[k].y, x4.y, a1);
            a2 = fmaf(w[k].z, x4.z, a2);
            a3 = fmaf(w[k].w, x4.w, a3);
        }
        zx[((size_t)b * TT + t) * 128 + r] = (a0 + a1) + (a2 + a3);
    }
}

// ---------------- Kernel 2: single-wave recurrence, v_dot2_f32_f16 dots ------------
// h1/h2 live in LDS as packed f16 (allgather = 4x ds_read_b128); all recurrent
// dot products use v_dot2_f32_f16 (2 MACs/inst, f32 accumulate) -> per-step
// dot instructions 232 -> 112. Spine order as R8: L0(t+1) main dot hides the
// h2 allgather; h1 allgather hides under L1's wh1 dot; q perm = 3 parallel
// shuffles. Weights pinned once per tile (R8: pins hold at this pressure).
__global__ void __launch_bounds__(64, 1)
lstm_pipe(const float* __restrict__ zx,      // [B,TT,128]
          const float* __restrict__ taup,
          const float* __restrict__ gumbel,  // [T,B,1,C]
          const float* __restrict__ w_ih0,   // [128,68] (ct cols 64..67)
          const float* __restrict__ w_hh0,   // [128,32]
          const float* __restrict__ w_ih1,   // [128,32]
          const float* __restrict__ w_hh1,   // [128,32]
          const float* __restrict__ b_ih1,
          const float* __restrict__ b_hh1,
          const float* __restrict__ w_lin,   // [4,32]
          const float* __restrict__ b_lin,   // [4]
          float* __restrict__ out)           // [B,T,4]
{
    const int b    = blockIdx.x;
    const int l    = threadIdx.x;     // 0..63
    const int half = l >> 5;
    const int rA   = l;               // rows l (i|f) and l+64 (g|o)
    const int rB   = l + 64;
    const int c    = l >> 4;          // q channel group

    __shared__ __align__(16) float zbuf[2][TILE][128];   // 16 KB, +1-shifted rows
    __shared__ __align__(16) float4 gbuf[2][TILE];
    __shared__ __align__(16) _Float16 h1h[HH];           // packed f16 h-state
    __shared__ __align__(16) _Float16 h2h[HH];

    // ---- per-lane weights: f32 wct (feedback), f16-pair bits for the dots ----
    f4 wctA = *(const f4*)(w_ih0 + (size_t)rA * 68 + 64);
    f4 wctB = *(const f4*)(w_ih0 + (size_t)rB * 68 + 64);
    float wh0A[16], wh0B[16], wi1A[16], wi1B[16], wh1A[16], wh1B[16], wlc[16];
#pragma unroll
    for (int k = 0; k < 8; ++k) {
        f4 w;
        w = *(const f4*)(w_hh0 + (size_t)rA * HH + 4 * k);
        wh0A[2 * k] = pk2(w.x, w.y); wh0A[2 * k + 1] = pk2(w.z, w.w);
        w = *(const f4*)(w_hh0 + (size_t)rB * HH + 4 * k);
        wh0B[2 * k] = pk2(w.x, w.y); wh0B[2 * k + 1] = pk2(w.z, w.w);
        w = *(const f4*)(w_ih1 + (size_t)rA * HH + 4 * k);
        wi1A[2 * k] = pk2(w.x, w.y); wi1A[2 * k + 1] = pk2(w.z, w.w);
        w = *(const f4*)(w_ih1 + (size_t)rB * HH + 4 * k);
        wi1B[2 * k] = pk2(w.x, w.y); wi1B[2 * k + 1] = pk2(w.z, w.w);
        w = *(const f4*)(w_hh1 + (size_t)rA * HH + 4 * k);
        wh1A[2 * k] = pk2(w.x, w.y); wh1A[2 * k + 1] = pk2(w.z, w.w);
        w = *(const f4*)(w_hh1 + (size_t)rB * HH + 4 * k);
        wh1B[2 * k] = pk2(w.x, w.y); wh1B[2 * k + 1] = pk2(w.z, w.w);
        w = *(const f4*)(w_lin + (size_t)c * HH + 4 * k);
        wlc[2 * k] = pk2(w.x, w.y); wlc[2 * k + 1] = pk2(w.z, w.w);
    }
    const float bias1A = b_ih1[rA] + b_hh1[rA];
    const float bias1B = b_ih1[rB] + b_hh1[rB];
    const float inv_tau = rcpf(taup[0]);
    const float blc = b_lin[c];

    const float* __restrict__ zb = zx + (size_t)b * TT * 128;
    float* __restrict__ ob = out + (size_t)b * TT * CC;
    const int srow = l >> 5;          // staging: f4 slot f=i*64+l -> row i*2+srow, col4 l&31
    const int scol = l & 31;

    // ---- stage tile 0: zx rows 1..16, gumbel t=0..15 ----
    {
        f4 sz[8];
#pragma unroll
        for (int i = 0; i < 8; ++i) {
            int row = 1 + i * 2 + srow;
            sz[i] = *(const f4*)(zb + (size_t)row * 128 + scol * 4);
        }
        float4 gv = *(const float4*)(gumbel + ((size_t)(l & 15) * BB + b) * CC);
#pragma unroll
        for (int i = 0; i < 8; ++i) ((f4*)&zbuf[0][0][0])[i * 64 + l] = sz[i];
        if (l < 16) gbuf[0][l] = gv;
    }

    float cst1 = 0.f, cst2 = 0.f;
    f4 h1g[4];                         // raw f16x8 views of h1 (4 VGPR-quads)

    // ---- prologue: h1(0), h2(0) (h,c init 0; ct0 = one-hot(0)) ----
    {
        float zA = zb[rA] + wctA.x;            // zx(0) already holds bias0
        float zB = zb[rB] + wctB.x;
        float zi, zf, zg, zo;
        COMBINE(zA, zB, zi, zf, zg, zo);
        (void)zf;
        cst1 = sigm(zi) * tanh_f(zg);          // sigm(zf)*0 dropped (exact)
        float h1n = sigm(zo) * tanh_f(cst1);
        if (l < HH) h1h[l] = (_Float16)h1n;
#pragma unroll
        for (int k2 = 0; k2 < 4; ++k2) h1g[k2] = ((const f4*)h1h)[k2];

        float bA0 = bias1A, bA1 = 0.f, bA2 = 0.f, bA3 = 0.f;
        float bB0 = bias1B, bB1 = 0.f, bB2 = 0.f, bB3 = 0.f;
        DOT32(bA0, bA1, bA2, bA3, wi1A, h1g);
        DOT32(bB0, bB1, bB2, bB3, wi1B, h1g);
        zA = (bA0 + bA1) + (bA2 + bA3);
        zB = (bB0 + bB1) + (bB2 + bB3);
        COMBINE(zA, zB, zi, zf, zg, zo);
        cst2 = sigm(zi) * tanh_f(zg);
        float h2n = sigm(zo) * tanh_f(cst2);
        if (l < HH) h2h[l] = (_Float16)h2n;
    }

    // ---- main loop: tiles of 16 steps, staging split in 8-step halves ----
    for (int k = 0; k < NT; ++k) {
        const int cb = k & 1, nb = cb ^ 1;
        const int kn = (k + 1 < NT) ? k + 1 : 0;   // harmless reload at the end
        float4 gv;

#pragma unroll
        for (int hf = 0; hf < 2; ++hf) {
            // issue staging loads for next-tile rows hf*8 .. hf*8+7 (4 f4/lane)
            f4 szh[4];
#pragma unroll
            for (int i = 0; i < 4; ++i) {
                int ii = hf * 4 + i;
                int row = kn * TILE + 1 + ii * 2 + srow;
                if (row > TT - 1) row = TT - 1;
                szh[i] = *(const f4*)(zb + (size_t)row * 128 + scol * 4);
            }
            if (hf == 0)
                gv = *(const float4*)(gumbel +
                        ((size_t)(kn * TILE + (l & 15)) * BB + b) * CC);

#pragma unroll 2
            for (int s8 = 0; s8 < 8; ++s8) {
                const int s = hf * 8 + s8;
                const int t = k * TILE + s;

                // (1) early LDS issues: zx(t+1), gumbel(t), h2(t) allgather (f16)
                const float zxnA = zbuf[cb][s][rA];
                const float zxnB = zbuf[cb][s][rB];
                const float4 gtc = gbuf[cb][s];
                f4 h2g[4];
#pragma unroll
                for (int k2 = 0; k2 < 4; ++k2) h2g[k2] = ((const f4*)h2h)[k2];

                // (2) L0(t+1) main dot: wh0 . h1(t)  (hides (1) latency)
                float aA0 = 0.f, aA1 = 0.f, aA2 = 0.f, aA3 = 0.f;
                float aB0 = 0.f, aB1 = 0.f, aB2 = 0.f, aB3 = 0.f;
                DOT32(aA0, aA1, aA2, aA3, wh0A, h1g);
                DOT32(aB0, aB1, aB2, aB3, wh0B, h1g);

                // (3) q(t) = blc + wlc . h2(t)
                float s0 = blc, s1 = 0.f, s2 = 0.f, s3 = 0.f;
                DOT32(s0, s1, s2, s3, wlc, h2g);
                float qown = (s0 + s1) + (s2 + s3);

                // (4) 3 PARALLEL perms + softmax((q+g)/tau) -> y(t)
                float t1 = __shfl_xor(qown, 16, 64);
                float t2 = __shfl_xor(qown, 32, 64);
                float t3 = __shfl_xor(qown, 48, 64);
                float q0 = (c == 0) ? qown : (c == 1) ? t1 : (c == 2) ? t2 : t3;
                float q1 = (c == 0) ? t1 : (c == 1) ? qown : (c == 2) ? t3 : t2;
                float q2 = (c == 0) ? t2 : (c == 1) ? t3 : (c == 2) ? qown : t1;
                float q3 = (c == 0) ? t3 : (c == 1) ? t2 : (c == 2) ? t1 : qown;
                float l0  = (q0 + gtc.x) * inv_tau;
                float l1_ = (q1 + gtc.y) * inv_tau;
                float l2  = (q2 + gtc.z) * inv_tau;
                float l3  = (q3 + gtc.w) * inv_tau;
                float m = fmaxf(fmaxf(l0, l1_), fmaxf(l2, l3));
                float e0 = __expf(l0 - m), e1 = __expf(l1_ - m);
                float e2 = __expf(l2 - m), e3 = __expf(l3 - m);
                float inv = rcpf((e0 + e1) + (e2 + e3));
                float y0 = e0 * inv, y1 = e1 * inv, y2 = e2 * inv, y3 = e3 * inv;
                if (l == 0)
                    *(float4*)(ob + (size_t)t * CC) = make_float4(y0, y1, y2, y3);

                // (5) L0 tail: + zx(t+1) + wct.y(t); combine; act -> h1(t+1)
                aA0 += zxnA; aB0 += zxnB;
                aA0 = fmaf(wctA.x, y0, aA0); aA1 = fmaf(wctA.y, y1, aA1);
                aA2 = fmaf(wctA.z, y2, aA2); aA3 = fmaf(wctA.w, y3, aA3);
                aB0 = fmaf(wctB.x, y0, aB0); aB1 = fmaf(wctB.y, y1, aB1);
                aB2 = fmaf(wctB.z, y2, aB2); aB3 = fmaf(wctB.w, y3, aB3);
                float zA = (aA0 + aA1) + (aA2 + aA3);
                float zB = (aB0 + aB1) + (aB2 + aB3);
                float zi, zf, zg, zo;
                COMBINE(zA, zB, zi, zf, zg, zo);
                cst1 = sigm(zf) * cst1 + sigm(zi) * tanh_f(zg);
                float h1n = sigm(zo) * tanh_f(cst1);
                if (l < HH) h1h[l] = (_Float16)h1n;

                // (6) h1(t+1) allgather (hidden by (7)'s wh1 dot)
#pragma unroll
                for (int k2 = 0; k2 < 4; ++k2) h1g[k2] = ((const f4*)h1h)[k2];

                // (7) L1(t+1): wh1 . h2(t) first, then wi1 . h1(t+1)
                float bA0 = bias1A, bA1 = 0.f, bA2 = 0.f, bA3 = 0.f;
                float bB0 = bias1B, bB1 = 0.f, bB2 = 0.f, bB3 = 0.f;
                DOT32(bA0, bA1, bA2, bA3, wh1A, h2g);
                DOT32(bB0, bB1, bB2, bB3, wh1B, h2g);
                DOT32(bA0, bA1, bA2, bA3, wi1A, h1g);
                DOT32(bB0, bB1, bB2, bB3, wi1B, h1g);
                zA = (bA0 + bA1) + (bA2 + bA3);
                zB = (bB0 + bB1) + (bB2 + bB3);
                COMBINE(zA, zB, zi, zf, zg, zo);
                cst2 = sigm(zf) * cst2 + sigm(zi) * tanh_f(zg);
                float h2n = sigm(zo) * tanh_f(cst2);
                if (l < HH) h2h[l] = (_Float16)h2n;
            }

            // commit this half's staged rows (>=8 steps of vmcnt slack)
#pragma unroll
            for (int i = 0; i < 4; ++i)
                ((f4*)&zbuf[nb][0][0])[(hf * 4 + i) * 64 + l] = szh[i];
        }
        if (l < 16) gbuf[nb][l] = gv;

        // ---- weight pins ONCE PER TILE (VGPR_Count < ~170 => remat returned) ----
        asm volatile("" : "+v"(wh0A[0]), "+v"(wh0A[1]), "+v"(wh0A[2]), "+v"(wh0A[3]),
                          "+v"(wh0A[4]), "+v"(wh0A[5]), "+v"(wh0A[6]), "+v"(wh0A[7]),
                          "+v"(wh0A[8]), "+v"(wh0A[9]), "+v"(wh0A[10]), "+v"(wh0A[11]),
                          "+v"(wh0A[12]), "+v"(wh0A[13]), "+v"(wh0A[14]), "+v"(wh0A[15]));
        asm volatile("" : "+v"(wh0B[0]), "+v"(wh0B[1]), "+v"(wh0B[2]), "+v"(wh0B[3]),
                          "+v"(wh0B[4]), "+v"(wh0B[5]), "+v"(wh0B[6]), "+v"(wh0B[7]),
                          "+v"(wh0B[8]), "+v"(wh0B[9]), "+v"(wh0B[10]), "+v"(wh0B[11]),
                          "+v"(wh0B[12]), "+v"(wh0B[13]), "+v"(wh0B[14]), "+v"(wh0B[15]));
        asm volatile("" : "+v"(wi1A[0]), "+v"(wi1A[1]), "+v"(wi1A[2]), "+v"(wi1A[3]),
                          "+v"(wi1A[4]), "+v"(wi1A[5]), "+v"(wi1A[6]), "+v"(wi1A[7]),
                          "+v"(wi1A[8]), "+v"(wi1A[9]), "+v"(wi1A[10]), "+v"(wi1A[11]),
                          "+v"(wi1A[12]), "+v"(wi1A[13]), "+v"(wi1A[14]), "+v"(wi1A[15]));
        asm volatile("" : "+v"(wi1B[0]), "+v"(wi1B[1]), "+v"(wi1B[2]), "+v"(wi1B[3]),
                          "+v"(wi1B[4]), "+v"(wi1B[5]), "+v"(wi1B[6]), "+v"(wi1B[7]),
                          "+v"(wi1B[8]), "+v"(wi1B[9]), "+v"(wi1B[10]), "+v"(wi1B[11]),
                          "+v"(wi1B[12]), "+v"(wi1B[13]), "+v"(wi1B[14]), "+v"(wi1B[15]));
        asm volatile("" : "+v"(wh1A[0]), "+v"(wh1A[1]), "+v"(wh1A[2]), "+v"(wh1A[3]),
                          "+v"(wh1A[4]), "+v"(wh1A[5]), "+v"(wh1A[6]), "+v"(wh1A[7]),
                          "+v"(wh1A[8]), "+v"(wh1A[9]), "+v"(wh1A[10]), "+v"(wh1A[11]),
                          "+v"(wh1A[12]), "+v"(wh1A[13]), "+v"(wh1A[14]), "+v"(wh1A[15]));
        asm volatile("" : "+v"(wh1B[0]), "+v"(wh1B[1]), "+v"(wh1B[2]), "+v"(wh1B[3]),
                          "+v"(wh1B[4]), "+v"(wh1B[5]), "+v"(wh1B[6]), "+v"(wh1B[7]),
                          "+v"(wh1B[8]), "+v"(wh1B[9]), "+v"(wh1B[10]), "+v"(wh1B[11]),
                          "+v"(wh1B[12]), "+v"(wh1B[13]), "+v"(wh1B[14]), "+v"(wh1B[15]));
        asm volatile("" : "+v"(wlc[0]), "+v"(wlc[1]), "+v"(wlc[2]), "+v"(wlc[3]),
                          "+v"(wlc[4]), "+v"(wlc[5]), "+v"(wlc[6]), "+v"(wlc[7]),
                          "+v"(wlc[8]), "+v"(wlc[9]), "+v"(wlc[10]), "+v"(wlc[11]),
                          "+v"(wlc[12]), "+v"(wlc[13]), "+v"(wlc[14]), "+v"(wlc[15]));
        asm volatile("" : "+v"(wctA), "+v"(wctB));
    }
}

// ---------------- Fallback (verbatim R3 kernel, used only if ws too small) ----------
extern "C" __global__ void __launch_bounds__(128, 2)
lstm_opt_enc(const float* __restrict__ states, const float* __restrict__ taup,
             const float* __restrict__ gumbel, const float* __restrict__ w_ih0,
             const float* __restrict__ w_hh0, const float* __restrict__ b_ih0,
             const float* __restrict__ b_hh0, const float* __restrict__ w_ih1,
             const float* __restrict__ w_hh1, const float* __restrict__ b_ih1,
             const float* __restrict__ b_hh1, const float* __restrict__ w_lin,
             const float* __restrict__ b_lin, float* __restrict__ out)
{
    const int b   = blockIdx.x;
    const int tid = threadIdx.x;
    const int l   = tid & 63;
    const int wv  = tid >> 6;
    const int u0  = l & 15;
    const int g   = l >> 4;
    const int u   = wv * 16 + u0;
    const int r   = g * 32 + u;

    __shared__ __align__(16) float xb[2][DD];
    __shared__ __align__(16) float h1b[2][HH];
    __shared__ __align__(16) float h2b[2][HH];

    float wi0r[68], wh0r[HH], wi1r[HH], wh1r[HH];
#pragma unroll
    for (int k = 0; k < 68; ++k) wi0r[k] = w_ih0[r * 68 + k];
#pragma unroll
    for (int k = 0; k < HH; ++k) wh0r[k] = w_hh0[r * HH + k];
#pragma unroll
    for (int k = 0; k < HH; ++k) wi1r[k] = w_ih1[r * HH + k];
#pragma unroll
    for (int k = 0; k < HH; ++k) wh1r[k] = w_hh1[r * HH + k];
    const float bias0 = b_ih0[r] + b_hh0[r];
    const float bias1 = b_ih1[r] + b_hh1[r];
    const float inv_tau = rcpf(taup[0]);
    const float wl0 = w_lin[g * HH + u0];
    const float wl1 = w_lin[g * HH + u0 + 16];
    const float blc = b_lin[g];

    float cst1 = 0.f, cst2 = 0.f;
    float y0 = 1.f, y1 = 0.f, y2 = 0.f, y3 = 0.f;

    const float* __restrict__ sb = states + (size_t)b * TT * DD;
    float* __restrict__ ob = out + (size_t)b * TT * CC;

    float xr = 0.f;
    if (tid < DD) xr = sb[tid];
    if (tid < HH) { h1b[0][tid] = 0.f; h2b[0][tid] = 0.f; }
    if (tid < DD) { xb[0][tid] = xr; xr = sb[DD + tid]; }
    __syncthreads();

    for (int t = 0; t < TT; ++t) {
        const int p = t & 1, np = p ^ 1;
        if (tid < DD) { xb[np][tid] = xr; }
        const int tn = (t + 2 < TT) ? t + 2 : TT - 1;
        if (tid < DD) { xr = sb[tn * DD + tid]; }
        const float4 gt = *(const float4*)(gumbel + ((size_t)t * BB + b) * CC);

        float a0 = bias0, a1 = 0.f, a2 = 0.f, a3 = 0.f;
        const float4* xv = (const float4*)xb[p];
#pragma unroll
        for (int k = 0; k < 16; ++k) {
            float4 x4 = xv[k];
            a0 = fmaf(wi0r[4 * k + 0], x4.x, a0);
            a1 = fmaf(wi0r[4 * k + 1], x4.y, a1);
            a2 = fmaf(wi0r[4 * k + 2], x4.z, a2);
            a3 = fmaf(wi0r[4 * k + 3], x4.w, a3);
        }
        a0 = fmaf(wi0r[64], y0, a0);
        a1 = fmaf(wi0r[65], y1, a1);
        a2 = fmaf(wi0r[66], y2, a2);
        a3 = fmaf(wi0r[67], y3, a3);
        const float4* h1v = (const float4*)h1b[p];
#pragma unroll
        for (int k = 0; k < 8; ++k) {
            float4 h4 = h1v[k];
            a0 = fmaf(wh0r[4 * k + 0], h4.x, a0);
            a1 = fmaf(wh0r[4 * k + 1], h4.y, a1);
            a2 = fmaf(wh0r[4 * k + 2], h4.z, a2);
            a3 = fmaf(wh0r[4 * k + 3], h4.w, a3);
        }
        float z = (a0 + a1) + (a2 + a3);
        float v1  = __shfl_xor(z, 16, 64);
        float lo  = (g & 1) ? v1 : z;
        float hi  = (g & 1) ? z  : v1;
        float lo2 = __shfl_xor(lo, 32, 64);
        float hi2 = __shfl_xor(hi, 32, 64);
        float zi = (g < 2) ? lo  : lo2;
        float zf = (g < 2) ? hi  : hi2;
        float zg = (g < 2) ? lo2 : lo;
        float zo = (g < 2) ? hi2 : hi;
        cst1 = sigm(zf) * cst1 + sigm(zi) * tanh_f(zg);
        float h1new = sigm(zo) * tanh_f(cst1);
        if (g == 0) h1b[np][u] = h1new;
        __syncthreads();

        a0 = bias1; a1 = 0.f; a2 = 0.f; a3 = 0.f;
        const float4* h1n = (const float4*)h1b[np];
        const float4* h2v = (const float4*)h2b[p];
#pragma unroll
        for (int k = 0; k < 8; ++k) {
            float4 h4 = h1n[k];
            float4 g4 = h2v[k];
            a0 = fmaf(wi1r[4 * k + 0], h4.x, a0);
            a1 = fmaf(wi1r[4 * k + 1], h4.y, a1);
            a2 = fmaf(wi1r[4 * k + 2], h4.z, a2);
            a3 = fmaf(wi1r[4 * k + 3], h4.w, a3);
            a0 = fmaf(wh1r[4 * k + 0], g4.x, a0);
            a1 = fmaf(wh1r[4 * k + 1], g4.y, a1);
            a2 = fmaf(wh1r[4 * k + 2], g4.z, a2);
            a3 = fmaf(wh1r[4 * k + 3], g4.w, a3);
        }
        z = (a0 + a1) + (a2 + a3);
        v1  = __shfl_xor(z, 16, 64);
        lo  = (g & 1) ? v1 : z;
        hi  = (g & 1) ? z  : v1;
        lo2 = __shfl_xor(lo, 32, 64);
        hi2 = __shfl_xor(hi, 32, 64);
        zi = (g < 2) ? lo  : lo2;
        zf = (g < 2) ? hi  : hi2;
        zg = (g < 2) ? lo2 : lo;
        zo = (g < 2) ? hi2 : hi;
        cst2 = sigm(zf) * cst2 + sigm(zi) * tanh_f(zg);
        float h2new = sigm(zo) * tanh_f(cst2);
        if (g == 0) h2b[np][u] = h2new;
        __syncthreads();

        float part = wl0 * h2b[np][u0] + wl1 * h2b[np][u0 + 16];
        part += __shfl_xor(part, 1, 64);
        part += __shfl_xor(part, 2, 64);
        part += __shfl_xor(part, 4, 64);
        part += __shfl_xor(part, 8, 64);
        float qown = part + blc;
        float t1 = __shfl_xor(qown, 16, 64);
        float t2 = __shfl_xor(qown, 32, 64);
        float t3 = __shfl_xor(t1, 32, 64);
        float q0 = (g == 0) ? qown : (g == 1) ? t1 : (g == 2) ? t2 : t3;
        float q1 = (g == 0) ? t1 : (g == 1) ? qown : (g == 2) ? t3 : t2;
        float q2 = (g == 0) ? t2 : (g == 1) ? t3 : (g == 2) ? qown : t1;
        float q3 = (g == 0) ? t3 : (g == 1) ? t2 : (g == 2) ? t1 : qown;
        float l0  = (q0 + gt.x) * inv_tau;
        float l1_ = (q1 + gt.y) * inv_tau;
        float l2  = (q2 + gt.z) * inv_tau;
        float l3  = (q3 + gt.w) * inv_tau;
        float m = fmaxf(fmaxf(l0, l1_), fmaxf(l2, l3));
        float e0 = __expf(l0 - m), e1 = __expf(l1_ - m);
        float e2 = __expf(l2 - m), e3 = __expf(l3 - m);
        float inv = rcpf((e0 + e1) + (e2 + e3));
        y0 = e0 * inv; y1 = e1 * inv; y2 = e2 * inv; y3 = e3 * inv;

        if (tid == 0) *(float4*)(ob + (size_t)t * CC) = make_float4(y0, y1, y2, y3);
    }
}

extern "C" void kernel_launch(void* const* d_in, const int* in_sizes, int n_in,
                              void* d_out, int out_size, void* d_ws, size_t ws_size,
                              hipStream_t stream) {
    const float* states = (const float*)d_in[0];
    const float* tau    = (const float*)d_in[1];
    const float* gumbel = (const float*)d_in[2];
    const float* w_ih0  = (const float*)d_in[3];
    const float* w_hh0  = (const float*)d_in[4];
    const float* b_ih0  = (const float*)d_in[5];
    const float* b_hh0  = (const float*)d_in[6];
    const float* w_ih1  = (const float*)d_in[7];
    const float* w_hh1  = (const float*)d_in[8];
    const float* b_ih1  = (const float*)d_in[9];
    const float* b_hh1  = (const float*)d_in[10];
    const float* w_lin  = (const float*)d_in[11];
    const float* b_lin  = (const float*)d_in[12];
    float* out = (float*)d_out;

    // need the full zx buffer [B][TT][128] f32 (empirically ws is big enough)
    const size_t zx_bytes = (size_t)BB * TT * 128 * 4;
    if (ws_size >= zx_bytes) {
        float* zx = (float*)d_ws;
        hipLaunchKernelGGL(zx_gemm, dim3(NT, BB), dim3(128), 0, stream,
                           states, w_ih0, b_ih0, b_hh0, zx);
        hipLaunchKernelGGL(lstm_pipe, dim3(BB), dim3(64), 0, stream,
                           zx, tau, gumbel, w_ih0, w_hh0, w_ih1, w_hh1,
                           b_ih1, b_hh1, w_lin, b_lin, out);
    } else {
        hipLaunchKernelGGL(lstm_opt_enc, dim3(BB), dim3(128), 0, stream,
                           states, tau, gumbel, w_ih0, w_hh0, b_ih0, b_hh0,
                           w_ih1, w_hh1, b_ih1, b_hh1, w_lin, b_lin, out);
    }
}